// Round 15
// baseline (267.859 us; speedup 1.0000x reference)
//
#include <hip/hip_runtime.h>
#include <math.h>

// SparseDiffAttn: B=1,H=12,N=2048,D=128, BM=64, top-k=192, static window [c-153,c+153),
// random keys via modern-JAX randint under jax_threefry_partitionable=True:
//   k1 = tf((0,1),(0,0)), k2 = tf((0,1),(0,1))        [fold-like split]
//   bits(k,i) = b1^b2 with (b1,b2) = tf(k,(0,i))      [partitionable random_bits]
//   offset = ((hi%100)*96 + lo%100) % 100; rnd <=> offset==0
// PRECISION: selection robust to ~1e-6 rel; split-fp16 MFMA (hi·hi+hi·lo+lo·hi) ~1e-7.
// R23 (412.7us): fragment-ordered operands killed the VMEM line-scatter wall.
// R24 (347.7us): k3 QK+PV on split-fp16 MFMA. R28 (272.4us): k2b equal-position list.
// R31 (262.4us): B-panel LDS staging in k1/k2r gave only ~8us — NOT L2-BW bound.
// DIAGNOSIS: whole pipeline is serial-chain/occupancy limited (k3: MfmaUtil 7.7 /
// VALU 22.7 / occ 26, invariant to all loop-body surgery; 768 blocks = 3/CU,
// 16-chunk serial chain each).
// R32 (this round): KEY-SPLIT k3. No running-max softmax => partials combine exactly:
// l = l0+l1, O_unnorm = O0+O1. Each (gg,half) computed by 2 blocks over chunk-aligned
// disjoint key ranges -> chain halves, grid 768->1536 (6 blocks/CU). Partials
// g_oacc[1536][32][128] f32 + g_lacc[1536][32]; k4_comb does (a0+a1)/(l0+l1)+OC.
// fp-add order change only (~1e-7, output-only; selection untouched).
// k0/k1/k2r/k2b byte-identical to R31.
constexpr int Hh   = 12;
constexpr int Nn   = 2048;
constexpr int Dd   = 128;
constexpr int BMq  = 64;
constexpr int QGg  = 32;            // Nn/BMq
constexpr int KSEL = 192;           // 64 * round(0.1*2048/64)
constexpr int CK   = 32;            // key chunk (k3)
constexpr float SCALE = 0.08838834764831845f;  // 1/sqrt(128)

typedef _Float16 v8h __attribute__((ext_vector_type(8)));   // MFMA A/B frag (4 VGPRs)
typedef float    v4f __attribute__((ext_vector_type(4)));   // MFMA C/D frag

// persistent scratch (fully rewritten every launch before any read)
__device__ __attribute__((aligned(16))) _Float16 g_qh[(size_t)Hh*Nn*Dd];  // Q*SCALE hi
__device__ __attribute__((aligned(16))) _Float16 g_ql[(size_t)Hh*Nn*Dd];  // Q*SCALE lo
__device__ __attribute__((aligned(16))) _Float16 g_kh[(size_t)Hh*Nn*Dd];  // K hi
__device__ __attribute__((aligned(16))) _Float16 g_kl[(size_t)Hh*Nn*Dd];  // K lo
__device__ float          g_lp[(size_t)Hh*Nn*16];           // per-jb partial row sums
__device__ float          g_bs[(size_t)Hh*QGg*Nn];          // colsum scores (3 MB)
__device__ unsigned short g_sel[Hh*QGg*Nn];
__device__ int            g_cnt[Hh*QGg];
__device__ __attribute__((aligned(16))) float g_oacc[(size_t)Hh*QGg*2*2*32*128]; // 25MB
__device__ float          g_lacc[(size_t)Hh*QGg*2*2*32];

__device__ __forceinline__ unsigned int rotl32(unsigned int x, int n){
  return (x << n) | (x >> (32 - n));
}

__device__ __forceinline__ unsigned pack2h(_Float16 a, _Float16 b){
  unsigned short ua, ub;
  __builtin_memcpy(&ua, &a, 2);
  __builtin_memcpy(&ub, &b, 2);
  return (unsigned)ua | ((unsigned)ub << 16);
}

// threefry2x32, 20 rounds, arbitrary key
__device__ __forceinline__ void tf2x32(unsigned int k0, unsigned int k1,
                                       unsigned int x0, unsigned int x1,
                                       unsigned int &o0, unsigned int &o1){
  const unsigned int ks2 = 0x1BD11BDAu ^ k0 ^ k1;
  x0 += k0; x1 += k1;
  x0 += x1; x1 = rotl32(x1,13); x1 ^= x0;
  x0 += x1; x1 = rotl32(x1,15); x1 ^= x0;
  x0 += x1; x1 = rotl32(x1,26); x1 ^= x0;
  x0 += x1; x1 = rotl32(x1, 6); x1 ^= x0;
  x0 += k1; x1 += ks2 + 1u;
  x0 += x1; x1 = rotl32(x1,17); x1 ^= x0;
  x0 += x1; x1 = rotl32(x1,29); x1 ^= x0;
  x0 += x1; x1 = rotl32(x1,16); x1 ^= x0;
  x0 += x1; x1 = rotl32(x1,24); x1 ^= x0;
  x0 += ks2; x1 += k0 + 2u;
  x0 += x1; x1 = rotl32(x1,13); x1 ^= x0;
  x0 += x1; x1 = rotl32(x1,15); x1 ^= x0;
  x0 += x1; x1 = rotl32(x1,26); x1 ^= x0;
  x0 += x1; x1 = rotl32(x1, 6); x1 ^= x0;
  x0 += k0; x1 += k1 + 3u;
  x0 += x1; x1 = rotl32(x1,17); x1 ^= x0;
  x0 += x1; x1 = rotl32(x1,29); x1 ^= x0;
  x0 += x1; x1 = rotl32(x1,16); x1 ^= x0;
  x0 += x1; x1 = rotl32(x1,24); x1 ^= x0;
  x0 += k1; x1 += ks2 + 4u;
  x0 += x1; x1 = rotl32(x1,13); x1 ^= x0;
  x0 += x1; x1 = rotl32(x1,15); x1 ^= x0;
  x0 += x1; x1 = rotl32(x1,26); x1 ^= x0;
  x0 += x1; x1 = rotl32(x1, 6); x1 ^= x0;
  x0 += ks2; x1 += k0 + 5u;
  o0 = x0; o1 = x1;
}

// partitionable-threefry randint(key(1), ..., 0, 100) == 0 for flat element idx
__device__ __forceinline__ bool jax_rand01(unsigned int idx,
                                           unsigned int k1a, unsigned int k1b,
                                           unsigned int k2a, unsigned int k2b){
  unsigned int h0, h1, l0, l1;
  tf2x32(k1a, k1b, 0u, idx, h0, h1);
  tf2x32(k2a, k2b, 0u, idx, l0, l1);
  unsigned int h = h0 ^ h1;
  unsigned int l = l0 ^ l1;
  unsigned int off = ((h % 100u) * 96u + (l % 100u)) % 100u;
  return off == 0u;
}

// ---------------- Kernel 0: split-fp16 convert + fragment-order relayout (NO LDS) ----------------
__global__ __launch_bounds__(256) void k0_cvt(const float* __restrict__ Q,
                                              const float* __restrict__ K){
  const int bid = blockIdx.x;          // h*128 + rb
  const int t = threadIdx.x;
  const int kc = t >> 6, ln = t & 63;
  const int row = ln & 15;
  const int col = kc*32 + (ln >> 4)*8;
  const size_t src = ((size_t)bid*16 + row)*Dd + col;
  const size_t ob  = (((size_t)bid)*4 + kc)*512 + (size_t)ln*8;

  float4 qa = *(const float4*)(Q + src);
  float4 qb = *(const float4*)(Q + src + 4);
  float qs[8] = {qa.x*SCALE, qa.y*SCALE, qa.z*SCALE, qa.w*SCALE,
                 qb.x*SCALE, qb.y*SCALE, qb.z*SCALE, qb.w*SCALE};
  v8h qh, ql;
  #pragma unroll
  for (int j = 0; j < 8; ++j){
    _Float16 hi = (_Float16)qs[j];
    qh[j] = hi;
    ql[j] = (_Float16)(qs[j] - (float)hi);
  }
  *(v8h*)&g_qh[ob] = qh;
  *(v8h*)&g_ql[ob] = ql;

  float4 ka = *(const float4*)(K + src);
  float4 kb = *(const float4*)(K + src + 4);
  float ks[8] = {ka.x, ka.y, ka.z, ka.w, kb.x, kb.y, kb.z, kb.w};
  v8h kh, kl;
  #pragma unroll
  for (int j = 0; j < 8; ++j){
    _Float16 hi = (_Float16)ks[j];
    kh[j] = hi;
    kl[j] = (_Float16)(ks[j] - (float)hi);
  }
  *(v8h*)&g_kh[ob] = kh;
  *(v8h*)&g_kl[ob] = kl;
}

// ---------------- Kernel 1: MFMA split-fp16 QK (B panel via LDS) -> rowsum partials ----------------
__global__ __launch_bounds__(256) void k1_rowsum(){
  const int bid0 = blockIdx.x;
  const int w = (bid0 & 7)*384 + (bid0 >> 3);   // 3072 blocks, xcd-contiguous
  const int jb = w & 15, gp = (w >> 4) & 15, h = w >> 8;
  const int t = threadIdx.x;
  const int wv = t >> 6, ln = t & 63;
  const int nidx = ln & 15, quad = ln >> 4;
  const size_t lnoff = (size_t)ln*8;
  const size_t habase = ((size_t)h*128 + gp*8 + wv*2)*4;  // +tr*4 +kc, then *512
  const size_t hbbase = ((size_t)h*128 + jb*8)*4;         // +tc*4 +kc, then *512

  __shared__ v8h Bh[2][8][64], Bl[2][8][64];
  const int f0 = t*2, f1 = t*2 + 1;
  const int tc0 = f0 >> 6, bln0 = f0 & 63;
  const int tc1 = f1 >> 6, bln1 = f1 & 63;

  v8h rbh0, rbh1, rbl0, rbl1;
  {
    const size_t a0 = (hbbase + tc0*4 + 0)*512 + (size_t)bln0*8;
    const size_t a1 = (hbbase + tc1*4 + 0)*512 + (size_t)bln1*8;
    rbh0 = *(const v8h*)&g_kh[a0]; rbh1 = *(const v8h*)&g_kh[a1];
    rbl0 = *(const v8h*)&g_kl[a0]; rbl1 = *(const v8h*)&g_kl[a1];
  }

  v4f acc[2][8];
  #pragma unroll
  for (int tr = 0; tr < 2; ++tr)
    #pragma unroll
    for (int tc = 0; tc < 8; ++tc)
      acc[tr][tc] = (v4f){0.f, 0.f, 0.f, 0.f};

  for (int kc = 0; kc < 4; ++kc){
    const int cur = kc & 1;
    Bh[cur][tc0][bln0] = rbh0; Bh[cur][tc1][bln1] = rbh1;
    Bl[cur][tc0][bln0] = rbl0; Bl[cur][tc1][bln1] = rbl1;
    __syncthreads();
    if (kc < 3){
      const size_t a0 = (hbbase + tc0*4 + kc+1)*512 + (size_t)bln0*8;
      const size_t a1 = (hbbase + tc1*4 + kc+1)*512 + (size_t)bln1*8;
      rbh0 = *(const v8h*)&g_kh[a0]; rbh1 = *(const v8h*)&g_kh[a1];
      rbl0 = *(const v8h*)&g_kl[a0]; rbl1 = *(const v8h*)&g_kl[a1];
    }
    v8h ahi[2], alo[2];
    #pragma unroll
    for (int tr = 0; tr < 2; ++tr){
      const size_t ab = (habase + tr*4 + kc)*512 + lnoff;
      ahi[tr] = *(const v8h*)&g_qh[ab];
      alo[tr] = *(const v8h*)&g_ql[ab];
    }
    #pragma unroll
    for (int tc = 0; tc < 8; ++tc){
      v8h bh = Bh[cur][tc][ln];
      v8h bl = Bl[cur][tc][ln];
      #pragma unroll
      for (int tr = 0; tr < 2; ++tr){
        acc[tr][tc] = __builtin_amdgcn_mfma_f32_16x16x32_f16(ahi[tr], bh, acc[tr][tc], 0, 0, 0);
        acc[tr][tc] = __builtin_amdgcn_mfma_f32_16x16x32_f16(ahi[tr], bl, acc[tr][tc], 0, 0, 0);
        acc[tr][tc] = __builtin_amdgcn_mfma_f32_16x16x32_f16(alo[tr], bh, acc[tr][tc], 0, 0, 0);
      }
    }
  }

  // epilogue: exp, shfl-reduced row sums -> g_lp (R1 order: bit-exact l)
  #pragma unroll
  for (int tr = 0; tr < 2; ++tr){
    float rs[4] = {0.f, 0.f, 0.f, 0.f};
    #pragma unroll
    for (int tc = 0; tc < 8; ++tc){
      #pragma unroll
      for (int r = 0; r < 4; ++r){
        rs[r] += __expf(acc[tr][tc][r]);
      }
    }
    #pragma unroll
    for (int r = 0; r < 4; ++r){
      float v = rs[r];
      v += __shfl_xor(v, 1);
      v += __shfl_xor(v, 2);
      v += __shfl_xor(v, 4);
      v += __shfl_xor(v, 8);
      rs[r] = v;
    }
    if (nidx == 0){
      #pragma unroll
      for (int r = 0; r < 4; ++r){
        const int row = (wv*2+tr)*16 + quad*4 + r;
        g_lp[((size_t)h*Nn + gp*128 + row)*16 + jb] = rs[r];
      }
    }
  }
}

// ---------------- Kernel 2r: MFMA QK recompute (B via LDS) -> weighted colsum -> g_bs ----------------
__global__ __launch_bounds__(256) void k2r_colsum(){
  const int bid0 = blockIdx.x;
  const int w = (bid0 & 7)*384 + (bid0 >> 3);   // 3072 blocks, xcd-contiguous
  const int jb = w & 15, gp = (w >> 4) & 15, h = w >> 8;
  const int t = threadIdx.x;
  const int wv = t >> 6, ln = t & 63;
  const int nidx = ln & 15, quad = ln >> 4;
  const size_t lnoff = (size_t)ln*8;
  const size_t habase = ((size_t)h*128 + gp*8 + wv*2)*4;
  const size_t hbbase = ((size_t)h*128 + jb*8)*4;

  __shared__ v8h Bh[2][8][64], Bl[2][8][64];
  __shared__ float il_s[128];
  __shared__ float part[4][128];
  const int f0 = t*2, f1 = t*2 + 1;
  const int tc0 = f0 >> 6, bln0 = f0 & 63;
  const int tc1 = f1 >> 6, bln1 = f1 & 63;

  v8h rbh0, rbh1, rbl0, rbl1;
  {
    const size_t a0 = (hbbase + tc0*4 + 0)*512 + (size_t)bln0*8;
    const size_t a1 = (hbbase + tc1*4 + 0)*512 + (size_t)bln1*8;
    rbh0 = *(const v8h*)&g_kh[a0]; rbh1 = *(const v8h*)&g_kh[a1];
    rbl0 = *(const v8h*)&g_kl[a0]; rbl1 = *(const v8h*)&g_kl[a1];
  }
  if (t < 128){
    const float* lp = &g_lp[((size_t)h*Nn + gp*128 + t)*16];
    float s = 0.f;
    #pragma unroll
    for (int x = 0; x < 16; ++x) s += lp[x];
    il_s[t] = 1.0f / s;
  }

  v4f acc[2][8];
  #pragma unroll
  for (int tr = 0; tr < 2; ++tr)
    #pragma unroll
    for (int tc = 0; tc < 8; ++tc)
      acc[tr][tc] = (v4f){0.f, 0.f, 0.f, 0.f};

  for (int kc = 0; kc < 4; ++kc){
    const int cur = kc & 1;
    Bh[cur][tc0][bln0] = rbh0; Bh[cur][tc1][bln1] = rbh1;
    Bl[cur][tc0][bln0] = rbl0; Bl[cur][tc1][bln1] = rbl1;
    __syncthreads();
    if (kc < 3){
      const size_t a0 = (hbbase + tc0*4 + kc+1)*512 + (size_t)bln0*8;
      const size_t a1 = (hbbase + tc1*4 + kc+1)*512 + (size_t)bln1*8;
      rbh0 = *(const v8h*)&g_kh[a0]; rbh1 = *(const v8h*)&g_kh[a1];
      rbl0 = *(const v8h*)&g_kl[a0]; rbl1 = *(const v8h*)&g_kl[a1];
    }
    v8h ahi[2], alo[2];
    #pragma unroll
    for (int tr = 0; tr < 2; ++tr){
      const size_t ab = (habase + tr*4 + kc)*512 + lnoff;
      ahi[tr] = *(const v8h*)&g_qh[ab];
      alo[tr] = *(const v8h*)&g_ql[ab];
    }
    #pragma unroll
    for (int tc = 0; tc < 8; ++tc){
      v8h bh = Bh[cur][tc][ln];
      v8h bl = Bl[cur][tc][ln];
      #pragma unroll
      for (int tr = 0; tr < 2; ++tr){
        acc[tr][tc] = __builtin_amdgcn_mfma_f32_16x16x32_f16(ahi[tr], bh, acc[tr][tc], 0, 0, 0);
        acc[tr][tc] = __builtin_amdgcn_mfma_f32_16x16x32_f16(ahi[tr], bl, acc[tr][tc], 0, 0, 0);
        acc[tr][tc] = __builtin_amdgcn_mfma_f32_16x16x32_f16(alo[tr], bh, acc[tr][tc], 0, 0, 0);
      }
    }
  }

  // weighted colsum epilogue. Wave wv covers tile rows [wv*32, wv*32+32).
  __syncthreads();   // il_s ready
  float csg[8];
  #pragma unroll
  for (int tc = 0; tc < 8; ++tc) csg[tc] = 0.f;
  #pragma unroll
  for (int tr = 0; tr < 2; ++tr){
    #pragma unroll
    for (int tc = 0; tc < 8; ++tc){
      float cs = 0.f;
      #pragma unroll
      for (int r = 0; r < 4; ++r){
        const int row = (wv*2+tr)*16 + quad*4 + r;
        cs += __expf(acc[tr][tc][r]) * il_s[row];
      }
      cs += __shfl_xor(cs, 16);   // sum across the 4 quads (16 rows of this tile-row)
      cs += __shfl_xor(cs, 32);
      csg[tc] += cs;
    }
  }
  if (ln < 16){                    // quad 0 publishes this wave's 128 col-partials
    #pragma unroll
    for (int tc = 0; tc < 8; ++tc) part[wv][tc*16 + nidx] = csg[tc];
  }
  __syncthreads();
  // waves 0+1 = rows 0..63 = group 2gp; waves 2+3 = group 2gp+1
  const int col = t & 127, grp = t >> 7;
  g_bs[((size_t)h*QGg + gp*2 + grp)*Nn + jb*128 + col] =
      part[grp*2][col] + part[grp*2 + 1][col];
}

// ---------------- Kernel 2b v3: radix select + equal-position list + mask -> key list ----------------
__global__ __launch_bounds__(256) void k2b_mask(){
  const int bid = blockIdx.x, g = bid % QGg, t = threadIdx.x;
  const int wv = t >> 6, lw = t & 63;
  __shared__ int hist[256];
  __shared__ int wsum[4];
  __shared__ int selb_s, selgt_s;
  __shared__ int csel;
  __shared__ int eqn;
  __shared__ int eqpos[Nn];      // positions with value == T (cap = Nn, can't overflow)
  const float* src = g_bs + (size_t)bid*Nn;
  float mine[8];
  {
    float4 a = *(const float4*)&src[t*4];
    float4 b = *(const float4*)&src[1024 + t*4];
    mine[0]=a.x; mine[1]=a.y; mine[2]=a.z; mine[3]=a.w;
    mine[4]=b.x; mine[5]=b.y; mine[6]=b.z; mine[7]=b.w;
  }
  if (t == 0){ csel = 0; eqn = 0; }
  unsigned int bu8[8];
  #pragma unroll
  for (int u = 0; u < 8; ++u) bu8[u] = __float_as_uint(mine[u]);

  unsigned int k1a, k1b, k2a, k2b;
  tf2x32(0u, 1u, 0u, 0u, k1a, k1b);
  tf2x32(0u, 1u, 0u, 1u, k2a, k2b);

  unsigned int pref = 0u;   // decided high bits of T
  unsigned int msk  = 0u;   // which bits are decided
  int rem = KSEL;           // rank (from largest) within current group
  #pragma unroll
  for (int pass = 3; pass >= 0; --pass){
    const int shift = pass*8;
    hist[t] = 0;
    __syncthreads();
    #pragma unroll
    for (int u = 0; u < 8; ++u){
      if ((bu8[u] & msk) == pref)
        atomicAdd(&hist[(bu8[u] >> shift) & 0xFFu], 1);
    }
    __syncthreads();
    const int hcnt = hist[t];
    int s = hcnt;                 // inclusive suffix sum within this wave's 64 bins
    #pragma unroll
    for (int d = 1; d < 64; d <<= 1){
      int tmp = __shfl_down(s, d);
      if (lw + d < 64) s += tmp;
    }
    if (lw == 0) wsum[wv] = s;    // total of this wave's 64 bins
    __syncthreads();
    int base = 0;
    #pragma unroll
    for (int w2 = 1; w2 < 4; ++w2) if (wv + w2 < 4) base += wsum[wv + w2];
    const int gt_incl = s + base;     // sum_{j >= t} hist[j]
    const int gt = gt_incl - hcnt;    // strict: sum_{j > t}
    if (gt < rem && gt_incl >= rem){ selb_s = t; selgt_s = gt; }
    __syncthreads();
    pref |= ((unsigned)selb_s) << shift;
    msk  |= 0xFFu << shift;
    rem  -= selgt_s;
  }
  const unsigned int T = pref;        // the KSEL-th largest value's bits
  const int need = rem;               // ties taken lowest-index-first (jax top_k)

  // collect positions of elements equal to T (multiplicity tiny; list order arbitrary)
  #pragma unroll
  for (int u = 0; u < 8; ++u){
    int j = (u < 4) ? (t*4 + u) : (1024 + t*4 + u - 4);
    if (bu8[u] == T){
      int s = atomicAdd(&eqn, 1);
      eqpos[s] = j;
    }
  }
  __syncthreads();
  const int en = eqn;

  const int lo = g*BMq + BMq/2 - 153;   // ws=int(0.15*2048)=307, ws//2=153
  const int hi = g*BMq + BMq/2 + 153;
  const int ssum = ((hi < Nn) ? hi : Nn) - ((lo > 0) ? lo : 0);
  const bool vqg = (ssum + KSEL) < Nn;  // always true at this config

  #pragma unroll
  for (int u = 0; u < 8; ++u){
    int j = (u < 4) ? (t*4 + u) : (1024 + t*4 + u - 4);
    unsigned int bu = bu8[u];
    bool topk = bu > T;
    if (!topk && bu == T){
      int tr = 0;
      for (int i = 0; i < en; ++i)
        tr += (eqpos[i] < j) ? 1 : 0;
      topk = (tr < need);
    }
    bool rnd = jax_rand01((unsigned)(bid*Nn + j), k1a, k1b, k2a, k2b);
    bool st  = (j >= lo) && (j < hi);
    bool selb = st || ((rnd || topk) && vqg);
    if (selb){
      int slot = atomicAdd(&csel, 1);
      g_sel[(size_t)bid*Nn + slot] = (unsigned short)j;
    }
  }
  __syncthreads();
  if (t == 0) g_cnt[bid] = csel;
}

// ---------------- Kernel 3 v4: key-split MFMA attention -> unnormalized partials ----------------
// Grid 1536: w -> (ks = w&1, pb = w>>1) with pb = gg*2+half. Block ks processes the
// chunk-aligned key range [ks*ch, min(c, (ks+1)*ch)), ch = ceil(nchunks/2)*CK.
// Writes g_oacc[pb*2+ks][32][128] (unnormalized PV) + g_lacc[pb*2+ks][32] (partial l).
// Structure per chunk identical to v3 (V split-f16 swizzled, T14 staging, 3 barriers).
__global__ __launch_bounds__(256) void k3_attn(const float* __restrict__ K,
                                               const float* __restrict__ V){
  const int bid0 = blockIdx.x;
  const int w    = (bid0 & 7)*192 + (bid0 >> 3);   // xcd-grouped work index
  const int ks   = w & 1;
  const int pb   = w >> 1;             // gg*2 + half
  const int half = pb & 1;
  const int gg   = pb >> 1;            // h*QGg + g
  const int h = gg / QGg, g = gg % QGg;
  const int t = threadIdx.x;
  const int wv = t >> 6, ln = t & 63;
  const int nidx = ln & 15, quad = ln >> 4;
  const int qtile = wv >> 1, kdt = wv & 1;

  __shared__ _Float16 kh_s[CK][136];   // K hi, row stride 272B (16B-aligned)
  __shared__ _Float16 kl_s[CK][136];   // K lo
  __shared__ _Float16 vTh[Dd][40];     // V hi transposed+swizzled, row 80B (16B-aligned)
  __shared__ _Float16 vTl[Dd][40];     // V lo
  __shared__ _Float16 p_h[32][40];     // P hi
  __shared__ _Float16 p_l[32][40];     // P lo
  __shared__ float    l_part[2][32];

  const int c = g_cnt[gg];
  const unsigned short* sel = g_sel + (size_t)gg*Nn;
  const int nch = (c + CK - 1) / CK;
  const int ch  = ((nch + 1) / 2) * CK;
  const int cbeg = ks * ch;
  const int cend = (c < cbeg + ch) ? c : (cbeg + ch);

  // hoisted Q A-fragments (pre-scaled split-fp16, fragment-ordered, L2-hot)
  const int rb = g*4 + half*2 + qtile;
  v8h aHi[4], aLo[4];
  #pragma unroll
  for (int kc = 0; kc < 4; ++kc){
    const size_t ab = (((size_t)h*128 + rb)*4 + kc)*512 + (size_t)ln*8;
    aHi[kc] = *(const v8h*)&g_qh[ab];
    aLo[kc] = *(const v8h*)&g_ql[ab];
  }

  if (t < 64) l_part[t >> 5][t & 31] = 0.0f;

  // prologue: stage first chunk of this range into registers
  float4 kreg[4], vreg[4];
  if (cbeg < cend){
    const int cc0 = ((cend - cbeg) < CK) ? (cend - cbeg) : CK;
    #pragma unroll
    for (int it = 0; it < 4; ++it){
      int e = it*256 + t, row = e >> 5, c4 = e & 31;
      int j = (row < cc0) ? (int)sel[cbeg + row] : 0;
      kreg[it] = ((const float4*)(K + ((size_t)h*Nn + j)*Dd))[c4];
      vreg[it] = ((const float4*)(V + ((size_t)h*Nn + j)*Dd))[c4];
    }
  }

  v4f acc[4];
  #pragma unroll
  for (int dt = 0; dt < 4; ++dt) acc[dt] = (v4f){0.f, 0.f, 0.f, 0.f};

  // PV read column group (swizzle self-undoing)
  const int cg = (quad ^ ((nidx >> 2) & 3)) * 8;

  for (int c0 = cbeg; c0 < cend; c0 += CK){
    const int cc = ((cend - c0) < CK) ? (cend - c0) : CK;
    // ---- phase 1: regs -> LDS (K cvt once; V cvt once, transposed+swizzled) ----
    #pragma unroll
    for (int it = 0; it < 4; ++it){
      int e = it*256 + t, row = e >> 5, c4 = e & 31;
      float4 kv = kreg[it];
      float xs[4] = {kv.x, kv.y, kv.z, kv.w};
      _Float16 hh[4], ll[4];
      #pragma unroll
      for (int m = 0; m < 4; ++m){
        _Float16 hi = (_Float16)xs[m];
        hh[m] = hi;
        ll[m] = (_Float16)(xs[m] - (float)hi);
      }
      *(unsigned*)&kh_s[row][c4*4 + 0] = pack2h(hh[0], hh[1]);
      *(unsigned*)&kh_s[row][c4*4 + 2] = pack2h(hh[2], hh[3]);
      *(unsigned*)&kl_s[row][c4*4 + 0] = pack2h(ll[0], ll[1]);
      *(unsigned*)&kl_s[row][c4*4 + 2] = pack2h(ll[2], ll[3]);
      float4 vv = vreg[it];
      float vs[4] = {vv.x, vv.y, vv.z, vv.w};
      const int swz = row ^ ((c4 & 3) << 3);   // d = c4*4+m -> (d>>2)&3 == c4&3
      #pragma unroll
      for (int m = 0; m < 4; ++m){
        _Float16 hi = (_Float16)vs[m];
        vTh[c4*4 + m][swz] = hi;
        vTl[c4*4 + m][swz] = (_Float16)(vs[m] - (float)hi);
      }
    }
    __syncthreads();   // barrier A: LDS ready
    // ---- T14: issue next chunk's gathers into regs (latency hides under QK+PV) ----
    {
      const int nc0 = c0 + CK;
      if (nc0 < cend){
        const int ncc = ((cend - nc0) < CK) ? (cend - nc0) : CK;
        #pragma unroll
        for (int it = 0; it < 4; ++it){
          int e = it*256 + t, row = e >> 5, c4 = e & 31;
          int j = (row < ncc) ? (int)sel[nc0 + row] : 0;
          kreg[it] = ((const float4*)(K + ((size_t)h*Nn + j)*Dd))[c4];
          vreg[it] = ((const float4*)(V + ((size_t)h*Nn + j)*Dd))[c4];
        }
      }
    }
    // ---- phase 2: QK pure MFMA; epilogue exp -> p f16 + shfl l-reduce ----
    v4f sc = (v4f){0.f, 0.f, 0.f, 0.f};
    #pragma unroll
    for (int kc = 0; kc < 4; ++kc){
      v8h bh = *(const v8h*)&kh_s[kdt*16 + nidx][kc*32 + quad*8];
      v8h bl = *(const v8h*)&kl_s[kdt*16 + nidx][kc*32 + quad*8];
      sc = __builtin_amdgcn_mfma_f32_16x16x32_f16(aHi[kc], bh, sc, 0, 0, 0);
      sc = __builtin_amdgcn_mfma_f32_16x16x32_f16(aHi[kc], bl, sc, 0, 0, 0);
      sc = __builtin_amdgcn_mfma_f32_16x16x32_f16(aLo[kc], bh, sc, 0, 0, 0);
    }
    {
      const int k_loc = kdt*16 + nidx;
      float rs[4];
      #pragma unroll
      for (int r = 0; r < 4; ++r){
        float sv = (k_loc < cc) ? __expf(sc[r]) : 0.f;
        rs[r] = sv;
        _Float16 hi = (_Float16)sv;
        const int row = qtile*16 + quad*4 + r;
        p_h[row][k_loc] = hi;
        p_l[row][k_loc] = (_Float16)(sv - (float)hi);
      }
      #pragma unroll
      for (int r = 0; r < 4; ++r){
        float v = rs[r];
        v += __shfl_xor(v, 1);
        v += __shfl_xor(v, 2);
        v += __shfl_xor(v, 4);
        v += __shfl_xor(v, 8);
        rs[r] = v;
      }
      if (nidx == 0){
        #pragma unroll
        for (int r = 0; r < 4; ++r)
          l_part[kdt][qtile*16 + quad*4 + r] += rs[r];
      }
    }
    __syncthreads();   // barrier B: P ready, QK reads of kh/kl done
    // ---- phase 3: PV — all-vector LDS reads, 12 MFMA, zero conversion ----
    {
      v8h ph = *(const v8h*)&p_h[qtile*16 + nidx][quad*8];
      v8h pl = *(const v8h*)&p_l[qtile*16 + nidx][quad*8];
      #pragma unroll
      for (int dt = 0; dt < 4; ++dt){
        const int d = (kdt*4 + dt)*16 + nidx;
        v8h vh = *(const v8h*)&vTh[d][cg];
        v8h vl = *(const v8h*)&vTl[d][cg];
        acc[dt] = __builtin_amdgcn_mfma_f32_16x16x32_f16(ph, vh, acc[dt], 0, 0, 0);
        acc[dt] = __builtin_amdgcn_mfma_f32_16x16x32_f16(ph, vl, acc[dt], 0, 0, 0);
        acc[dt] = __builtin_amdgcn_mfma_f32_16x16x32_f16(pl, vh, acc[dt], 0, 0, 0);
      }
    }
    __syncthreads();   // barrier C: LDS consumed, safe to overwrite
  }

  // epilogue: unnormalized partials (l_part writes ordered by last barrier; if the
  // range was empty, everything is zero — still written so k4 can sum blindly)
  __syncthreads();
  const size_t pbase = ((size_t)pb*2 + ks)*4096;
  if (t < 32) g_lacc[((size_t)pb*2 + ks)*32 + t] = l_part[0][t] + l_part[1][t];
  #pragma unroll
  for (int dt = 0; dt < 4; ++dt){
    const int d = (kdt*4 + dt)*16 + nidx;
    #pragma unroll
    for (int r = 0; r < 4; ++r){
      const int row = qtile*16 + quad*4 + r;
      g_oacc[pbase + (size_t)row*128 + d] = acc[dt][r];
    }
  }
}

// ---------------- Kernel 4: combine key-split partials -> out ----------------
__global__ __launch_bounds__(256) void k4_comb(const float* __restrict__ OC,
                                               float* __restrict__ out){
  const int pb = blockIdx.x;           // gg*2 + half
  const int half = pb & 1;
  const int gg = pb >> 1;
  const int h = gg / QGg, g = gg % QGg;
  const int t = threadIdx.x;
  __shared__ float il_s[32];
  if (t < 32){
    float l0 = g_lacc[((size_t)pb*2 + 0)*32 + t];
    float l1 = g_lacc[((size_t)pb*2 + 1)*32 + t];
    il_s[t] = 1.0f / (l0 + l1);
  }
  __syncthreads();
  const size_t b0 = ((size_t)pb*2 + 0)*4096;
  const size_t b1 = ((size_t)pb*2 + 1)*4096;
  #pragma unroll
  for (int i = 0; i < 4; ++i){
    int e = i*256 + t;                 // 1024 float4 = 32 rows x 32 f4
    int row = e >> 5, c4 = e & 31;
    float4 a0 = *(const float4*)&g_oacc[b0 + (size_t)row*128 + c4*4];
    float4 a1 = *(const float4*)&g_oacc[b1 + (size_t)row*128 + c4*4];
    const float il = il_s[row];
    const size_t o = ((size_t)h*Nn + (size_t)g*BMq + half*32 + row)*Dd + c4*4;
    float4 oc = *(const float4*)(OC + o);
    float4 rr;
    rr.x = (a0.x + a1.x)*il + oc.x;
    rr.y = (a0.y + a1.y)*il + oc.y;
    rr.z = (a0.z + a1.z)*il + oc.z;
    rr.w = (a0.w + a1.w)*il + oc.w;
    *(float4*)(out + o) = rr;
  }
}

extern "C" void kernel_launch(void* const* d_in, const int* in_sizes, int n_in,
                              void* d_out, int out_size, void* d_ws, size_t ws_size,
                              hipStream_t stream) {
  (void)in_sizes; (void)n_in; (void)out_size; (void)d_ws; (void)ws_size;
  const float* Q  = (const float*)d_in[0];
  const float* K  = (const float*)d_in[1];
  const float* V  = (const float*)d_in[2];
  const float* OC = (const float*)d_in[3];
  float* out = (float*)d_out;
  hipLaunchKernelGGL(k0_cvt,     dim3(Hh*128),     dim3(256), 0, stream, Q, K);
  hipLaunchKernelGGL(k1_rowsum,  dim3(Hh*16*16),   dim3(256), 0, stream);
  hipLaunchKernelGGL(k2r_colsum, dim3(Hh*16*16),   dim3(256), 0, stream);
  hipLaunchKernelGGL(k2b_mask,   dim3(Hh*QGg),     dim3(256), 0, stream);
  hipLaunchKernelGGL(k3_attn,    dim3(Hh*QGg*2*2), dim3(256), 0, stream, K, V);
  hipLaunchKernelGGL(k4_comb,    dim3(Hh*QGg*2),   dim3(256), 0, stream, OC, out);
}

// Round 17
// 255.969 us; speedup vs baseline: 1.0464x; 1.0464x over previous
//
#include <hip/hip_runtime.h>
#include <math.h>

// SparseDiffAttn: B=1,H=12,N=2048,D=128, BM=64, top-k=192, static window [c-153,c+153),
// random keys via modern-JAX randint under jax_threefry_partitionable=True:
//   k1 = tf((0,1),(0,0)), k2 = tf((0,1),(0,1))        [fold-like split]
//   bits(k,i) = b1^b2 with (b1,b2) = tf(k,(0,i))      [partitionable random_bits]
//   offset = ((hi%100)*96 + lo%100) % 100; rnd <=> offset==0
// PRECISION: selection robust to ~1e-6 rel; split-fp16 MFMA (hi·hi+hi·lo+lo·hi) ~1e-7.
// R23 (412.7us): fragment-ordered operands killed the VMEM line-scatter wall.
// R24 (347.7us): k3 QK+PV on split-fp16 MFMA. R28 (272.4us): k2b equal-position list.
// R31 (262.4us BEST): B-panel LDS staging (reg-staged). R32 (267.9us): key-split k3
// REGRESSED — k3 invariant (LDS caps 3 blocks/CU; split = 2 sequential rounds).
// R33/R34 (R34 = R33 resubmitted; R33 failed at container acquisition — 4th instance of
// the infra signature, 3/3 prior resubmits passed; gload_lds contract re-audited:
// wave-uniform LDS base + lane*16B dest, per-lane contiguous src, literal size=16,
// barrier-parity double-buffer race-free):
// (1) k3 reverted to R31 fused form. (2) k1/k2r B staging via
// __builtin_amdgcn_global_load_lds width=16 (m151: reg-staged 646 TF vs gload_lds
// 874 TF at this tile). Bit-exact vs R31.
constexpr int Hh   = 12;
constexpr int Nn   = 2048;
constexpr int Dd   = 128;
constexpr int BMq  = 64;
constexpr int QGg  = 32;            // Nn/BMq
constexpr int KSEL = 192;           // 64 * round(0.1*2048/64)
constexpr int CK   = 32;            // key chunk (k3)
constexpr float SCALE = 0.08838834764831845f;  // 1/sqrt(128)

typedef _Float16 v8h __attribute__((ext_vector_type(8)));   // MFMA A/B frag (4 VGPRs)
typedef float    v4f __attribute__((ext_vector_type(4)));   // MFMA C/D frag

// persistent scratch (fully rewritten every launch before any read)
// fragment-ordered: offset(h,rb,kc,ln,e) = (((h*128+rb)*4+kc)*64+ln)*8+e holds original
// element (row = rb*16 + (ln&15), col = kc*32 + (ln>>4)*8 + e).
__device__ __attribute__((aligned(16))) _Float16 g_qh[(size_t)Hh*Nn*Dd];  // Q*SCALE hi
__device__ __attribute__((aligned(16))) _Float16 g_ql[(size_t)Hh*Nn*Dd];  // Q*SCALE lo
__device__ __attribute__((aligned(16))) _Float16 g_kh[(size_t)Hh*Nn*Dd];  // K hi
__device__ __attribute__((aligned(16))) _Float16 g_kl[(size_t)Hh*Nn*Dd];  // K lo
__device__ float          g_lp[(size_t)Hh*Nn*16];           // per-jb partial row sums
__device__ float          g_bs[(size_t)Hh*QGg*Nn];          // colsum scores (3 MB)
__device__ unsigned short g_sel[Hh*QGg*Nn];
__device__ int            g_cnt[Hh*QGg];

__device__ __forceinline__ unsigned int rotl32(unsigned int x, int n){
  return (x << n) | (x >> (32 - n));
}

__device__ __forceinline__ unsigned pack2h(_Float16 a, _Float16 b){
  unsigned short ua, ub;
  __builtin_memcpy(&ua, &a, 2);
  __builtin_memcpy(&ub, &b, 2);
  return (unsigned)ua | ((unsigned)ub << 16);
}

// async global->LDS, 16B/lane: per-lane global src, WAVE-UNIFORM lds base (+lane*16)
__device__ __forceinline__ void gload16(const _Float16* gsrc_lane, v8h* lds_base){
  __builtin_amdgcn_global_load_lds(
      (const __attribute__((address_space(1))) void*)gsrc_lane,
      (__attribute__((address_space(3))) void*)lds_base, 16, 0, 0);
}

// threefry2x32, 20 rounds, arbitrary key
__device__ __forceinline__ void tf2x32(unsigned int k0, unsigned int k1,
                                       unsigned int x0, unsigned int x1,
                                       unsigned int &o0, unsigned int &o1){
  const unsigned int ks2 = 0x1BD11BDAu ^ k0 ^ k1;
  x0 += k0; x1 += k1;
  x0 += x1; x1 = rotl32(x1,13); x1 ^= x0;
  x0 += x1; x1 = rotl32(x1,15); x1 ^= x0;
  x0 += x1; x1 = rotl32(x1,26); x1 ^= x0;
  x0 += x1; x1 = rotl32(x1, 6); x1 ^= x0;
  x0 += k1; x1 += ks2 + 1u;
  x0 += x1; x1 = rotl32(x1,17); x1 ^= x0;
  x0 += x1; x1 = rotl32(x1,29); x1 ^= x0;
  x0 += x1; x1 = rotl32(x1,16); x1 ^= x0;
  x0 += x1; x1 = rotl32(x1,24); x1 ^= x0;
  x0 += ks2; x1 += k0 + 2u;
  x0 += x1; x1 = rotl32(x1,13); x1 ^= x0;
  x0 += x1; x1 = rotl32(x1,15); x1 ^= x0;
  x0 += x1; x1 = rotl32(x1,26); x1 ^= x0;
  x0 += x1; x1 = rotl32(x1, 6); x1 ^= x0;
  x0 += k0; x1 += k1 + 3u;
  x0 += x1; x1 = rotl32(x1,17); x1 ^= x0;
  x0 += x1; x1 = rotl32(x1,29); x1 ^= x0;
  x0 += x1; x1 = rotl32(x1,16); x1 ^= x0;
  x0 += x1; x1 = rotl32(x1,24); x1 ^= x0;
  x0 += k1; x1 += ks2 + 4u;
  x0 += x1; x1 = rotl32(x1,13); x1 ^= x0;
  x0 += x1; x1 = rotl32(x1,15); x1 ^= x0;
  x0 += x1; x1 = rotl32(x1,26); x1 ^= x0;
  x0 += x1; x1 = rotl32(x1, 6); x1 ^= x0;
  x0 += ks2; x1 += k0 + 5u;
  o0 = x0; o1 = x1;
}

// partitionable-threefry randint(key(1), ..., 0, 100) == 0 for flat element idx
__device__ __forceinline__ bool jax_rand01(unsigned int idx,
                                           unsigned int k1a, unsigned int k1b,
                                           unsigned int k2a, unsigned int k2b){
  unsigned int h0, h1, l0, l1;
  tf2x32(k1a, k1b, 0u, idx, h0, h1);
  tf2x32(k2a, k2b, 0u, idx, l0, l1);
  unsigned int h = h0 ^ h1;
  unsigned int l = l0 ^ l1;
  unsigned int off = ((h % 100u) * 96u + (l % 100u)) % 100u;
  return off == 0u;
}

// ---------------- Kernel 0: split-fp16 convert + fragment-order relayout (NO LDS) ----------------
__global__ __launch_bounds__(256) void k0_cvt(const float* __restrict__ Q,
                                              const float* __restrict__ K){
  const int bid = blockIdx.x;          // h*128 + rb
  const int t = threadIdx.x;
  const int kc = t >> 6, ln = t & 63;
  const int row = ln & 15;
  const int col = kc*32 + (ln >> 4)*8;
  const size_t src = ((size_t)bid*16 + row)*Dd + col;
  const size_t ob  = (((size_t)bid)*4 + kc)*512 + (size_t)ln*8;

  float4 qa = *(const float4*)(Q + src);
  float4 qb = *(const float4*)(Q + src + 4);
  float qs[8] = {qa.x*SCALE, qa.y*SCALE, qa.z*SCALE, qa.w*SCALE,
                 qb.x*SCALE, qb.y*SCALE, qb.z*SCALE, qb.w*SCALE};
  v8h qh, ql;
  #pragma unroll
  for (int j = 0; j < 8; ++j){
    _Float16 hi = (_Float16)qs[j];
    qh[j] = hi;
    ql[j] = (_Float16)(qs[j] - (float)hi);
  }
  *(v8h*)&g_qh[ob] = qh;
  *(v8h*)&g_ql[ob] = ql;

  float4 ka = *(const float4*)(K + src);
  float4 kb = *(const float4*)(K + src + 4);
  float ks[8] = {ka.x, ka.y, ka.z, ka.w, kb.x, kb.y, kb.z, kb.w};
  v8h kh, kl;
  #pragma unroll
  for (int j = 0; j < 8; ++j){
    _Float16 hi = (_Float16)ks[j];
    kh[j] = hi;
    kl[j] = (_Float16)(ks[j] - (float)hi);
  }
  *(v8h*)&g_kh[ob] = kh;
  *(v8h*)&g_kl[ob] = kl;
}

// ---------------- Kernel 1: MFMA split-fp16 QK (B via global_load_lds) -> rowsum partials ----------------
// 128x128 tile, 4 waves x (2 tile-rows x 8 tile-cols). B panel staged via async
// global_load_lds (16B/lane, wave-uniform LDS base, per-lane contiguous source),
// double-buffered; next-kc issued right after each barrier so loads fly under MFMA.
// Wave wv stages tc = {2wv, 2wv+1} for Bh and Bl (4 instructions/kc/wave).
__global__ __launch_bounds__(256) void k1_rowsum(){
  const int bid0 = blockIdx.x;
  const int w = (bid0 & 7)*384 + (bid0 >> 3);   // 3072 blocks, xcd-contiguous
  const int jb = w & 15, gp = (w >> 4) & 15, h = w >> 8;
  const int t = threadIdx.x;
  const int wv = t >> 6, ln = t & 63;
  const int nidx = ln & 15, quad = ln >> 4;
  const size_t lnoff = (size_t)ln*8;
  const size_t habase = ((size_t)h*128 + gp*8 + wv*2)*4;  // +tr*4 +kc, then *512
  const size_t hbbase = ((size_t)h*128 + jb*8)*4;         // +tc*4 +kc, then *512

  __shared__ v8h Bh[2][8][64], Bl[2][8][64];
  const int stc0 = wv*2, stc1 = wv*2 + 1;

  // prologue: stage kc=0 into buffer 0 (async)
  gload16(&g_kh[(hbbase + stc0*4 + 0)*512 + lnoff], &Bh[0][stc0][0]);
  gload16(&g_kh[(hbbase + stc1*4 + 0)*512 + lnoff], &Bh[0][stc1][0]);
  gload16(&g_kl[(hbbase + stc0*4 + 0)*512 + lnoff], &Bl[0][stc0][0]);
  gload16(&g_kl[(hbbase + stc1*4 + 0)*512 + lnoff], &Bl[0][stc1][0]);

  v4f acc[2][8];
  #pragma unroll
  for (int tr = 0; tr < 2; ++tr)
    #pragma unroll
    for (int tc = 0; tc < 8; ++tc)
      acc[tr][tc] = (v4f){0.f, 0.f, 0.f, 0.f};

  for (int kc = 0; kc < 4; ++kc){
    const int cur = kc & 1;
    __syncthreads();   // buf[cur] complete (compiler drains vmcnt before barrier)
    if (kc < 3){
      const int nxt = cur ^ 1;
      gload16(&g_kh[(hbbase + stc0*4 + kc+1)*512 + lnoff], &Bh[nxt][stc0][0]);
      gload16(&g_kh[(hbbase + stc1*4 + kc+1)*512 + lnoff], &Bh[nxt][stc1][0]);
      gload16(&g_kl[(hbbase + stc0*4 + kc+1)*512 + lnoff], &Bl[nxt][stc0][0]);
      gload16(&g_kl[(hbbase + stc1*4 + kc+1)*512 + lnoff], &Bl[nxt][stc1][0]);
    }
    v8h ahi[2], alo[2];
    #pragma unroll
    for (int tr = 0; tr < 2; ++tr){
      const size_t ab = (habase + tr*4 + kc)*512 + lnoff;
      ahi[tr] = *(const v8h*)&g_qh[ab];
      alo[tr] = *(const v8h*)&g_ql[ab];
    }
    #pragma unroll
    for (int tc = 0; tc < 8; ++tc){
      v8h bh = Bh[cur][tc][ln];
      v8h bl = Bl[cur][tc][ln];
      #pragma unroll
      for (int tr = 0; tr < 2; ++tr){
        acc[tr][tc] = __builtin_amdgcn_mfma_f32_16x16x32_f16(ahi[tr], bh, acc[tr][tc], 0, 0, 0);
        acc[tr][tc] = __builtin_amdgcn_mfma_f32_16x16x32_f16(ahi[tr], bl, acc[tr][tc], 0, 0, 0);
        acc[tr][tc] = __builtin_amdgcn_mfma_f32_16x16x32_f16(alo[tr], bh, acc[tr][tc], 0, 0, 0);
      }
    }
  }

  // epilogue: exp, shfl-reduced row sums -> g_lp (R1 order: bit-exact l)
  #pragma unroll
  for (int tr = 0; tr < 2; ++tr){
    float rs[4] = {0.f, 0.f, 0.f, 0.f};
    #pragma unroll
    for (int tc = 0; tc < 8; ++tc){
      #pragma unroll
      for (int r = 0; r < 4; ++r){
        rs[r] += __expf(acc[tr][tc][r]);
      }
    }
    #pragma unroll
    for (int r = 0; r < 4; ++r){
      float v = rs[r];
      v += __shfl_xor(v, 1);
      v += __shfl_xor(v, 2);
      v += __shfl_xor(v, 4);
      v += __shfl_xor(v, 8);
      rs[r] = v;
    }
    if (nidx == 0){
      #pragma unroll
      for (int r = 0; r < 4; ++r){
        const int row = (wv*2+tr)*16 + quad*4 + r;
        g_lp[((size_t)h*Nn + gp*128 + row)*16 + jb] = rs[r];
      }
    }
  }
}

// ---------------- Kernel 2r: MFMA QK recompute (B via global_load_lds) -> colsum -> g_bs ----------------
__global__ __launch_bounds__(256) void k2r_colsum(){
  const int bid0 = blockIdx.x;
  const int w = (bid0 & 7)*384 + (bid0 >> 3);   // 3072 blocks, xcd-contiguous
  const int jb = w & 15, gp = (w >> 4) & 15, h = w >> 8;
  const int t = threadIdx.x;
  const int wv = t >> 6, ln = t & 63;
  const int nidx = ln & 15, quad = ln >> 4;
  const size_t lnoff = (size_t)ln*8;
  const size_t habase = ((size_t)h*128 + gp*8 + wv*2)*4;
  const size_t hbbase = ((size_t)h*128 + jb*8)*4;

  __shared__ v8h Bh[2][8][64], Bl[2][8][64];
  __shared__ float il_s[128];
  __shared__ float part[4][128];
  const int stc0 = wv*2, stc1 = wv*2 + 1;

  // prologue: stage kc=0 into buffer 0 (async; latency overlaps il_s work)
  gload16(&g_kh[(hbbase + stc0*4 + 0)*512 + lnoff], &Bh[0][stc0][0]);
  gload16(&g_kh[(hbbase + stc1*4 + 0)*512 + lnoff], &Bh[0][stc1][0]);
  gload16(&g_kl[(hbbase + stc0*4 + 0)*512 + lnoff], &Bl[0][stc0][0]);
  gload16(&g_kl[(hbbase + stc1*4 + 0)*512 + lnoff], &Bl[0][stc1][0]);

  if (t < 128){
    const float* lp = &g_lp[((size_t)h*Nn + gp*128 + t)*16];
    float s = 0.f;
    #pragma unroll
    for (int x = 0; x < 16; ++x) s += lp[x];
    il_s[t] = 1.0f / s;
  }

  v4f acc[2][8];
  #pragma unroll
  for (int tr = 0; tr < 2; ++tr)
    #pragma unroll
    for (int tc = 0; tc < 8; ++tc)
      acc[tr][tc] = (v4f){0.f, 0.f, 0.f, 0.f};

  for (int kc = 0; kc < 4; ++kc){
    const int cur = kc & 1;
    __syncthreads();   // buf[cur] complete (+ il_s covered by first barrier)
    if (kc < 3){
      const int nxt = cur ^ 1;
      gload16(&g_kh[(hbbase + stc0*4 + kc+1)*512 + lnoff], &Bh[nxt][stc0][0]);
      gload16(&g_kh[(hbbase + stc1*4 + kc+1)*512 + lnoff], &Bh[nxt][stc1][0]);
      gload16(&g_kl[(hbbase + stc0*4 + kc+1)*512 + lnoff], &Bl[nxt][stc0][0]);
      gload16(&g_kl[(hbbase + stc1*4 + kc+1)*512 + lnoff], &Bl[nxt][stc1][0]);
    }
    v8h ahi[2], alo[2];
    #pragma unroll
    for (int tr = 0; tr < 2; ++tr){
      const size_t ab = (habase + tr*4 + kc)*512 + lnoff;
      ahi[tr] = *(const v8h*)&g_qh[ab];
      alo[tr] = *(const v8h*)&g_ql[ab];
    }
    #pragma unroll
    for (int tc = 0; tc < 8; ++tc){
      v8h bh = Bh[cur][tc][ln];
      v8h bl = Bl[cur][tc][ln];
      #pragma unroll
      for (int tr = 0; tr < 2; ++tr){
        acc[tr][tc] = __builtin_amdgcn_mfma_f32_16x16x32_f16(ahi[tr], bh, acc[tr][tc], 0, 0, 0);
        acc[tr][tc] = __builtin_amdgcn_mfma_f32_16x16x32_f16(ahi[tr], bl, acc[tr][tc], 0, 0, 0);
        acc[tr][tc] = __builtin_amdgcn_mfma_f32_16x16x32_f16(alo[tr], bh, acc[tr][tc], 0, 0, 0);
      }
    }
  }

  // weighted colsum epilogue. Wave wv covers tile rows [wv*32, wv*32+32).
  __syncthreads();   // all compute done; il_s stable
  float csg[8];
  #pragma unroll
  for (int tc = 0; tc < 8; ++tc) csg[tc] = 0.f;
  #pragma unroll
  for (int tr = 0; tr < 2; ++tr){
    #pragma unroll
    for (int tc = 0; tc < 8; ++tc){
      float cs = 0.f;
      #pragma unroll
      for (int r = 0; r < 4; ++r){
        const int row = (wv*2+tr)*16 + quad*4 + r;
        cs += __expf(acc[tr][tc][r]) * il_s[row];
      }
      cs += __shfl_xor(cs, 16);   // sum across the 4 quads (16 rows of this tile-row)
      cs += __shfl_xor(cs, 32);
      csg[tc] += cs;
    }
  }
  if (ln < 16){                    // quad 0 publishes this wave's 128 col-partials
    #pragma unroll
    for (int tc = 0; tc < 8; ++tc) part[wv][tc*16 + nidx] = csg[tc];
  }
  __syncthreads();
  // waves 0+1 = rows 0..63 = group 2gp; waves 2+3 = group 2gp+1
  const int col = t & 127, grp = t >> 7;
  g_bs[((size_t)h*QGg + gp*2 + grp)*Nn + jb*128 + col] =
      part[grp*2][col] + part[grp*2 + 1][col];
}

// ---------------- Kernel 2b v3: radix select + equal-position list + mask -> key list ----------------
__global__ __launch_bounds__(256) void k2b_mask(){
  const int bid = blockIdx.x, g = bid % QGg, t = threadIdx.x;
  const int wv = t >> 6, lw = t & 63;
  __shared__ int hist[256];
  __shared__ int wsum[4];
  __shared__ int selb_s, selgt_s;
  __shared__ int csel;
  __shared__ int eqn;
  __shared__ int eqpos[Nn];      // positions with value == T (cap = Nn, can't overflow)
  const float* src = g_bs + (size_t)bid*Nn;
  float mine[8];
  {
    float4 a = *(const float4*)&src[t*4];
    float4 b = *(const float4*)&src[1024 + t*4];
    mine[0]=a.x; mine[1]=a.y; mine[2]=a.z; mine[3]=a.w;
    mine[4]=b.x; mine[5]=b.y; mine[6]=b.z; mine[7]=b.w;
  }
  if (t == 0){ csel = 0; eqn = 0; }
  unsigned int bu8[8];
  #pragma unroll
  for (int u = 0; u < 8; ++u) bu8[u] = __float_as_uint(mine[u]);

  unsigned int k1a, k1b, k2a, k2b;
  tf2x32(0u, 1u, 0u, 0u, k1a, k1b);
  tf2x32(0u, 1u, 0u, 1u, k2a, k2b);

  unsigned int pref = 0u;   // decided high bits of T
  unsigned int msk  = 0u;   // which bits are decided
  int rem = KSEL;           // rank (from largest) within current group
  #pragma unroll
  for (int pass = 3; pass >= 0; --pass){
    const int shift = pass*8;
    hist[t] = 0;
    __syncthreads();
    #pragma unroll
    for (int u = 0; u < 8; ++u){
      if ((bu8[u] & msk) == pref)
        atomicAdd(&hist[(bu8[u] >> shift) & 0xFFu], 1);
    }
    __syncthreads();
    const int hcnt = hist[t];
    int s = hcnt;                 // inclusive suffix sum within this wave's 64 bins
    #pragma unroll
    for (int d = 1; d < 64; d <<= 1){
      int tmp = __shfl_down(s, d);
      if (lw + d < 64) s += tmp;
    }
    if (lw == 0) wsum[wv] = s;    // total of this wave's 64 bins
    __syncthreads();
    int base = 0;
    #pragma unroll
    for (int w2 = 1; w2 < 4; ++w2) if (wv + w2 < 4) base += wsum[wv + w2];
    const int gt_incl = s + base;     // sum_{j >= t} hist[j]
    const int gt = gt_incl - hcnt;    // strict: sum_{j > t}
    if (gt < rem && gt_incl >= rem){ selb_s = t; selgt_s = gt; }
    __syncthreads();
    pref |= ((unsigned)selb_s) << shift;
    msk  |= 0xFFu << shift;
    rem  -= selgt_s;
  }
  const unsigned int T = pref;        // the KSEL-th largest value's bits
  const int need = rem;               // ties taken lowest-index-first (jax top_k)

  // collect positions of elements equal to T (multiplicity tiny; list order arbitrary)
  #pragma unroll
  for (int u = 0; u < 8; ++u){
    int j = (u < 4) ? (t*4 + u) : (1024 + t*4 + u - 4);
    if (bu8[u] == T){
      int s = atomicAdd(&eqn, 1);
      eqpos[s] = j;
    }
  }
  __syncthreads();
  const int en = eqn;

  const int lo = g*BMq + BMq/2 - 153;   // ws=int(0.15*2048)=307, ws//2=153
  const int hi = g*BMq + BMq/2 + 153;
  const int ssum = ((hi < Nn) ? hi : Nn) - ((lo > 0) ? lo : 0);
  const bool vqg = (ssum + KSEL) < Nn;  // always true at this config

  #pragma unroll
  for (int u = 0; u < 8; ++u){
    int j = (u < 4) ? (t*4 + u) : (1024 + t*4 + u - 4);
    unsigned int bu = bu8[u];
    bool topk = bu > T;
    if (!topk && bu == T){
      int tr = 0;
      for (int i = 0; i < en; ++i)
        tr += (eqpos[i] < j) ? 1 : 0;
      topk = (tr < need);
    }
    bool rnd = jax_rand01((unsigned)(bid*Nn + j), k1a, k1b, k2a, k2b);
    bool st  = (j >= lo) && (j < hi);
    bool selb = st || ((rnd || topk) && vqg);
    if (selb){
      int slot = atomicAdd(&csel, 1);
      g_sel[(size_t)bid*Nn + slot] = (unsigned short)j;
    }
  }
  __syncthreads();
  if (t == 0) g_cnt[bid] = csel;
}

// ---------------- Kernel 3 v3: MFMA attention, V split-f16 swizzled, T14 async staging ----------------
__global__ __launch_bounds__(256) void k3_attn(const float* __restrict__ K,
                                               const float* __restrict__ V,
                                               const float* __restrict__ OC,
                                               float* __restrict__ out){
  const int bid0 = blockIdx.x;
  const int w    = (bid0 & 7)*96 + (bid0 >> 3);   // xcd-grouped work index
  const int half = w & 1;
  const int gg   = w >> 1;             // h*QGg + g
  const int h = gg / QGg, g = gg % QGg;
  const int t = threadIdx.x;
  const int wv = t >> 6, ln = t & 63;
  const int nidx = ln & 15, quad = ln >> 4;
  const int qtile = wv >> 1, kdt = wv & 1;

  __shared__ _Float16 kh_s[CK][136];   // K hi, row stride 272B (16B-aligned)
  __shared__ _Float16 kl_s[CK][136];   // K lo
  __shared__ _Float16 vTh[Dd][40];     // V hi transposed+swizzled, row 80B (16B-aligned)
  __shared__ _Float16 vTl[Dd][40];     // V lo
  __shared__ _Float16 p_h[32][40];     // P hi
  __shared__ _Float16 p_l[32][40];     // P lo
  __shared__ float    l_part[2][32];
  __shared__ float    l_s[32];

  const int c = g_cnt[gg];
  const unsigned short* sel = g_sel + (size_t)gg*Nn;

  // hoisted Q A-fragments (pre-scaled split-fp16, fragment-ordered, L2-hot)
  const int rb = g*4 + half*2 + qtile;
  v8h aHi[4], aLo[4];
  #pragma unroll
  for (int kc = 0; kc < 4; ++kc){
    const size_t ab = (((size_t)h*128 + rb)*4 + kc)*512 + (size_t)ln*8;
    aHi[kc] = *(const v8h*)&g_qh[ab];
    aLo[kc] = *(const v8h*)&g_ql[ab];
  }

  if (t < 64) l_part[t >> 5][t & 31] = 0.0f;

  // prologue: stage chunk 0 into registers
  float4 kreg[4], vreg[4];
  {
    const int cc0 = (c < CK) ? c : CK;
    #pragma unroll
    for (int it = 0; it < 4; ++it){
      int e = it*256 + t, row = e >> 5, c4 = e & 31;
      int j = (row < cc0) ? (int)sel[row] : 0;
      kreg[it] = ((const float4*)(K + ((size_t)h*Nn + j)*Dd))[c4];
      vreg[it] = ((const float4*)(V + ((size_t)h*Nn + j)*Dd))[c4];
    }
  }

  v4f acc[4];
  #pragma unroll
  for (int dt = 0; dt < 4; ++dt) acc[dt] = (v4f){0.f, 0.f, 0.f, 0.f};

  // PV read column group (swizzle self-undoing)
  const int cg = (quad ^ ((nidx >> 2) & 3)) * 8;

  for (int c0 = 0; c0 < c; c0 += CK){
    const int cc = ((c - c0) < CK) ? (c - c0) : CK;
    // ---- phase 1: regs -> LDS (K cvt once; V cvt once, transposed+swizzled) ----
    #pragma unroll
    for (int it = 0; it < 4; ++it){
      int e = it*256 + t, row = e >> 5, c4 = e & 31;
      float4 kv = kreg[it];
      float xs[4] = {kv.x, kv.y, kv.z, kv.w};
      _Float16 hh[4], ll[4];
      #pragma unroll
      for (int m = 0; m < 4; ++m){
        _Float16 hi = (_Float16)xs[m];
        hh[m] = hi;
        ll[m] = (_Float16)(xs[m] - (float)hi);
      }
      *(unsigned*)&kh_s[row][c4*4 + 0] = pack2h(hh[0], hh[1]);
      *(unsigned*)&kh_s[row][c4*4 + 2] = pack2h(hh[2], hh[3]);
      *(unsigned*)&kl_s[row][c4*4 + 0] = pack2h(ll[0], ll[1]);
      *(unsigned*)&kl_s[row][c4*4 + 2] = pack2h(ll[2], ll[3]);
      float4 vv = vreg[it];
      float vs[4] = {vv.x, vv.y, vv.z, vv.w};
      const int swz = row ^ ((c4 & 3) << 3);   // d = c4*4+m -> (d>>2)&3 == c4&3
      #pragma unroll
      for (int m = 0; m < 4; ++m){
        _Float16 hi = (_Float16)vs[m];
        vTh[c4*4 + m][swz] = hi;
        vTl[c4*4 + m][swz] = (_Float16)(vs[m] - (float)hi);
      }
    }
    __syncthreads();   // barrier A: LDS ready
    // ---- T14: issue next chunk's gathers into regs (latency hides under QK+PV) ----
    {
      const int nc0 = c0 + CK;
      if (nc0 < c){
        const int ncc = ((c - nc0) < CK) ? (c - nc0) : CK;
        #pragma unroll
        for (int it = 0; it < 4; ++it){
          int e = it*256 + t, row = e >> 5, c4 = e & 31;
          int j = (row < ncc) ? (int)sel[nc0 + row] : 0;
          kreg[it] = ((const float4*)(K + ((size_t)h*Nn + j)*Dd))[c4];
          vreg[it] = ((const float4*)(V + ((size_t)h*Nn + j)*Dd))[c4];
        }
      }
    }
    // ---- phase 2: QK pure MFMA; epilogue exp -> p f16 + shfl l-reduce ----
    v4f sc = (v4f){0.f, 0.f, 0.f, 0.f};
    #pragma unroll
    for (int kc = 0; kc < 4; ++kc){
      v8h bh = *(const v8h*)&kh_s[kdt*16 + nidx][kc*32 + quad*8];
      v8h bl = *(const v8h*)&kl_s[kdt*16 + nidx][kc*32 + quad*8];
      sc = __builtin_amdgcn_mfma_f32_16x16x32_f16(aHi[kc], bh, sc, 0, 0, 0);
      sc = __builtin_amdgcn_mfma_f32_16x16x32_f16(aHi[kc], bl, sc, 0, 0, 0);
      sc = __builtin_amdgcn_mfma_f32_16x16x32_f16(aLo[kc], bh, sc, 0, 0, 0);
    }
    {
      const int k_loc = kdt*16 + nidx;
      float rs[4];
      #pragma unroll
      for (int r = 0; r < 4; ++r){
        float sv = (k_loc < cc) ? __expf(sc[r]) : 0.f;
        rs[r] = sv;
        _Float16 hi = (_Float16)sv;
        const int row = qtile*16 + quad*4 + r;
        p_h[row][k_loc] = hi;
        p_l[row][k_loc] = (_Float16)(sv - (float)hi);
      }
      #pragma unroll
      for (int r = 0; r < 4; ++r){
        float v = rs[r];
        v += __shfl_xor(v, 1);
        v += __shfl_xor(v, 2);
        v += __shfl_xor(v, 4);
        v += __shfl_xor(v, 8);
        rs[r] = v;
      }
      if (nidx == 0){
        #pragma unroll
        for (int r = 0; r < 4; ++r)
          l_part[kdt][qtile*16 + quad*4 + r] += rs[r];
      }
    }
    __syncthreads();   // barrier B: P ready, QK reads of kh/kl done
    // ---- phase 3: PV — all-vector LDS reads, 12 MFMA, zero conversion ----
    {
      v8h ph = *(const v8h*)&p_h[qtile*16 + nidx][quad*8];
      v8h pl = *(const v8h*)&p_l[qtile*16 + nidx][quad*8];
      #pragma unroll
      for (int dt = 0; dt < 4; ++dt){
        const int d = (kdt*4 + dt)*16 + nidx;
        v8h vh = *(const v8h*)&vTh[d][cg];
        v8h vl = *(const v8h*)&vTl[d][cg];
        acc[dt] = __builtin_amdgcn_mfma_f32_16x16x32_f16(ph, vh, acc[dt], 0, 0, 0);
        acc[dt] = __builtin_amdgcn_mfma_f32_16x16x32_f16(ph, vl, acc[dt], 0, 0, 0);
        acc[dt] = __builtin_amdgcn_mfma_f32_16x16x32_f16(pl, vh, acc[dt], 0, 0, 0);
      }
    }
    __syncthreads();   // barrier C: LDS consumed, safe to overwrite
  }

  if (t < 32) l_s[t] = 1.0f / (l_part[0][t] + l_part[1][t]);
  __syncthreads();

  #pragma unroll
  for (int dt = 0; dt < 4; ++dt){
    const int d = (kdt*4 + dt)*16 + nidx;
    #pragma unroll
    for (int r = 0; r < 4; ++r){
      const int row = qtile*16 + quad*4 + r;
      const float il = l_s[row];
      const size_t o = ((size_t)h*Nn + (size_t)g*BMq + half*32 + row)*Dd + d;
      out[o] = acc[dt][r]*il + OC[o];
    }
  }
}

extern "C" void kernel_launch(void* const* d_in, const int* in_sizes, int n_in,
                              void* d_out, int out_size, void* d_ws, size_t ws_size,
                              hipStream_t stream) {
  (void)in_sizes; (void)n_in; (void)out_size; (void)d_ws; (void)ws_size;
  const float* Q  = (const float*)d_in[0];
  const float* K  = (const float*)d_in[1];
  const float* V  = (const float*)d_in[2];
  const float* OC = (const float*)d_in[3];
  float* out = (float*)d_out;
  hipLaunchKernelGGL(k0_cvt,     dim3(Hh*128),   dim3(256), 0, stream, Q, K);
  hipLaunchKernelGGL(k1_rowsum,  dim3(Hh*16*16), dim3(256), 0, stream);
  hipLaunchKernelGGL(k2r_colsum, dim3(Hh*16*16), dim3(256), 0, stream);
  hipLaunchKernelGGL(k2b_mask,   dim3(Hh*QGg),   dim3(256), 0, stream);
  hipLaunchKernelGGL(k3_attn,    dim3(Hh*QGg*2), dim3(256), 0, stream, K, V, OC, out);
}

// Round 18
// 232.832 us; speedup vs baseline: 1.1504x; 1.0994x over previous
//
#include <hip/hip_runtime.h>
#include <math.h>

// SparseDiffAttn: B=1,H=12,N=2048,D=128, BM=64, top-k=192, static window [c-153,c+153),
// random keys via modern-JAX randint under jax_threefry_partitionable=True:
//   k1 = tf((0,1),(0,0)), k2 = tf((0,1),(0,1))        [fold-like split]
//   bits(k,i) = b1^b2 with (b1,b2) = tf(k,(0,i))      [partitionable random_bits]
//   offset = ((hi%100)*96 + lo%100) % 100; rnd <=> offset==0
// PRECISION: SELECTION path (k0/k1/k2r/k2b) certified ~1e-6 -> split-fp16 everywhere.
// OUTPUT path (k3) only needs absmax band (~1e-2): QK kept split (cheap insurance for
// exp), PV single-fp16 (P_hi x V_hi; ~1e-3 abs on O, l stays exact fp32).
// R23 (412.7us): fragment-ordered operands killed the VMEM line-scatter wall.
// R24 (347.7us): k3 QK+PV MFMA. R28 (272.4us): k2b equal-position list.
// R31 (262.4us): B-panel LDS staging. R34 (256.0us BEST): B via global_load_lds.
// All kernels now latency/occupancy-bound (counters: nothing saturated; k3 occ 26%).
// R35 (this round): k3 PV single-fp16 -> 12->4 MFMA/chunk-wave, p_l/vTl deleted,
// LDS 43.5->~30KB -> 5 blocks/CU (from 3), first occupancy lever in k3's history.
// k1/k2r: #pragma unroll kc loop (software-pipeline A loads). Selection bit-exact.
constexpr int Hh   = 12;
constexpr int Nn   = 2048;
constexpr int Dd   = 128;
constexpr int BMq  = 64;
constexpr int QGg  = 32;            // Nn/BMq
constexpr int KSEL = 192;           // 64 * round(0.1*2048/64)
constexpr int CK   = 32;            // key chunk (k3)
constexpr float SCALE = 0.08838834764831845f;  // 1/sqrt(128)

typedef _Float16 v8h __attribute__((ext_vector_type(8)));   // MFMA A/B frag (4 VGPRs)
typedef float    v4f __attribute__((ext_vector_type(4)));   // MFMA C/D frag

// persistent scratch (fully rewritten every launch before any read)
// fragment-ordered: offset(h,rb,kc,ln,e) = (((h*128+rb)*4+kc)*64+ln)*8+e holds original
// element (row = rb*16 + (ln&15), col = kc*32 + (ln>>4)*8 + e).
__device__ __attribute__((aligned(16))) _Float16 g_qh[(size_t)Hh*Nn*Dd];  // Q*SCALE hi
__device__ __attribute__((aligned(16))) _Float16 g_ql[(size_t)Hh*Nn*Dd];  // Q*SCALE lo
__device__ __attribute__((aligned(16))) _Float16 g_kh[(size_t)Hh*Nn*Dd];  // K hi
__device__ __attribute__((aligned(16))) _Float16 g_kl[(size_t)Hh*Nn*Dd];  // K lo
__device__ float          g_lp[(size_t)Hh*Nn*16];           // per-jb partial row sums
__device__ float          g_bs[(size_t)Hh*QGg*Nn];          // colsum scores (3 MB)
__device__ unsigned short g_sel[Hh*QGg*Nn];
__device__ int            g_cnt[Hh*QGg];

__device__ __forceinline__ unsigned int rotl32(unsigned int x, int n){
  return (x << n) | (x >> (32 - n));
}

__device__ __forceinline__ unsigned pack2h(_Float16 a, _Float16 b){
  unsigned short ua, ub;
  __builtin_memcpy(&ua, &a, 2);
  __builtin_memcpy(&ub, &b, 2);
  return (unsigned)ua | ((unsigned)ub << 16);
}

// async global->LDS, 16B/lane: per-lane global src, WAVE-UNIFORM lds base (+lane*16)
__device__ __forceinline__ void gload16(const _Float16* gsrc_lane, v8h* lds_base){
  __builtin_amdgcn_global_load_lds(
      (const __attribute__((address_space(1))) void*)gsrc_lane,
      (__attribute__((address_space(3))) void*)lds_base, 16, 0, 0);
}

// threefry2x32, 20 rounds, arbitrary key
__device__ __forceinline__ void tf2x32(unsigned int k0, unsigned int k1,
                                       unsigned int x0, unsigned int x1,
                                       unsigned int &o0, unsigned int &o1){
  const unsigned int ks2 = 0x1BD11BDAu ^ k0 ^ k1;
  x0 += k0; x1 += k1;
  x0 += x1; x1 = rotl32(x1,13); x1 ^= x0;
  x0 += x1; x1 = rotl32(x1,15); x1 ^= x0;
  x0 += x1; x1 = rotl32(x1,26); x1 ^= x0;
  x0 += x1; x1 = rotl32(x1, 6); x1 ^= x0;
  x0 += k1; x1 += ks2 + 1u;
  x0 += x1; x1 = rotl32(x1,17); x1 ^= x0;
  x0 += x1; x1 = rotl32(x1,29); x1 ^= x0;
  x0 += x1; x1 = rotl32(x1,16); x1 ^= x0;
  x0 += x1; x1 = rotl32(x1,24); x1 ^= x0;
  x0 += ks2; x1 += k0 + 2u;
  x0 += x1; x1 = rotl32(x1,13); x1 ^= x0;
  x0 += x1; x1 = rotl32(x1,15); x1 ^= x0;
  x0 += x1; x1 = rotl32(x1,26); x1 ^= x0;
  x0 += x1; x1 = rotl32(x1, 6); x1 ^= x0;
  x0 += k0; x1 += k1 + 3u;
  x0 += x1; x1 = rotl32(x1,17); x1 ^= x0;
  x0 += x1; x1 = rotl32(x1,29); x1 ^= x0;
  x0 += x1; x1 = rotl32(x1,16); x1 ^= x0;
  x0 += x1; x1 = rotl32(x1,24); x1 ^= x0;
  x0 += k1; x1 += ks2 + 4u;
  x0 += x1; x1 = rotl32(x1,13); x1 ^= x0;
  x0 += x1; x1 = rotl32(x1,15); x1 ^= x0;
  x0 += x1; x1 = rotl32(x1,26); x1 ^= x0;
  x0 += x1; x1 = rotl32(x1, 6); x1 ^= x0;
  x0 += ks2; x1 += k0 + 5u;
  o0 = x0; o1 = x1;
}

// partitionable-threefry randint(key(1), ..., 0, 100) == 0 for flat element idx
__device__ __forceinline__ bool jax_rand01(unsigned int idx,
                                           unsigned int k1a, unsigned int k1b,
                                           unsigned int k2a, unsigned int k2b){
  unsigned int h0, h1, l0, l1;
  tf2x32(k1a, k1b, 0u, idx, h0, h1);
  tf2x32(k2a, k2b, 0u, idx, l0, l1);
  unsigned int h = h0 ^ h1;
  unsigned int l = l0 ^ l1;
  unsigned int off = ((h % 100u) * 96u + (l % 100u)) % 100u;
  return off == 0u;
}

// ---------------- Kernel 0: split-fp16 convert + fragment-order relayout (NO LDS) ----------------
__global__ __launch_bounds__(256) void k0_cvt(const float* __restrict__ Q,
                                              const float* __restrict__ K){
  const int bid = blockIdx.x;          // h*128 + rb
  const int t = threadIdx.x;
  const int kc = t >> 6, ln = t & 63;
  const int row = ln & 15;
  const int col = kc*32 + (ln >> 4)*8;
  const size_t src = ((size_t)bid*16 + row)*Dd + col;
  const size_t ob  = (((size_t)bid)*4 + kc)*512 + (size_t)ln*8;

  float4 qa = *(const float4*)(Q + src);
  float4 qb = *(const float4*)(Q + src + 4);
  float qs[8] = {qa.x*SCALE, qa.y*SCALE, qa.z*SCALE, qa.w*SCALE,
                 qb.x*SCALE, qb.y*SCALE, qb.z*SCALE, qb.w*SCALE};
  v8h qh, ql;
  #pragma unroll
  for (int j = 0; j < 8; ++j){
    _Float16 hi = (_Float16)qs[j];
    qh[j] = hi;
    ql[j] = (_Float16)(qs[j] - (float)hi);
  }
  *(v8h*)&g_qh[ob] = qh;
  *(v8h*)&g_ql[ob] = ql;

  float4 ka = *(const float4*)(K + src);
  float4 kb = *(const float4*)(K + src + 4);
  float ks[8] = {ka.x, ka.y, ka.z, ka.w, kb.x, kb.y, kb.z, kb.w};
  v8h kh, kl;
  #pragma unroll
  for (int j = 0; j < 8; ++j){
    _Float16 hi = (_Float16)ks[j];
    kh[j] = hi;
    kl[j] = (_Float16)(ks[j] - (float)hi);
  }
  *(v8h*)&g_kh[ob] = kh;
  *(v8h*)&g_kl[ob] = kl;
}

// ---------------- Kernel 1: MFMA split-fp16 QK (B via global_load_lds) -> rowsum partials ----------------
__global__ __launch_bounds__(256) void k1_rowsum(){
  const int bid0 = blockIdx.x;
  const int w = (bid0 & 7)*384 + (bid0 >> 3);   // 3072 blocks, xcd-contiguous
  const int jb = w & 15, gp = (w >> 4) & 15, h = w >> 8;
  const int t = threadIdx.x;
  const int wv = t >> 6, ln = t & 63;
  const int nidx = ln & 15, quad = ln >> 4;
  const size_t lnoff = (size_t)ln*8;
  const size_t habase = ((size_t)h*128 + gp*8 + wv*2)*4;  // +tr*4 +kc, then *512
  const size_t hbbase = ((size_t)h*128 + jb*8)*4;         // +tc*4 +kc, then *512

  __shared__ v8h Bh[2][8][64], Bl[2][8][64];
  const int stc0 = wv*2, stc1 = wv*2 + 1;

  // prologue: stage kc=0 into buffer 0 (async)
  gload16(&g_kh[(hbbase + stc0*4 + 0)*512 + lnoff], &Bh[0][stc0][0]);
  gload16(&g_kh[(hbbase + stc1*4 + 0)*512 + lnoff], &Bh[0][stc1][0]);
  gload16(&g_kl[(hbbase + stc0*4 + 0)*512 + lnoff], &Bl[0][stc0][0]);
  gload16(&g_kl[(hbbase + stc1*4 + 0)*512 + lnoff], &Bl[0][stc1][0]);

  v4f acc[2][8];
  #pragma unroll
  for (int tr = 0; tr < 2; ++tr)
    #pragma unroll
    for (int tc = 0; tc < 8; ++tc)
      acc[tr][tc] = (v4f){0.f, 0.f, 0.f, 0.f};

  #pragma unroll
  for (int kc = 0; kc < 4; ++kc){
    const int cur = kc & 1;
    __syncthreads();   // buf[cur] complete (compiler drains vmcnt before barrier)
    if (kc < 3){
      const int nxt = cur ^ 1;
      gload16(&g_kh[(hbbase + stc0*4 + kc+1)*512 + lnoff], &Bh[nxt][stc0][0]);
      gload16(&g_kh[(hbbase + stc1*4 + kc+1)*512 + lnoff], &Bh[nxt][stc1][0]);
      gload16(&g_kl[(hbbase + stc0*4 + kc+1)*512 + lnoff], &Bl[nxt][stc0][0]);
      gload16(&g_kl[(hbbase + stc1*4 + kc+1)*512 + lnoff], &Bl[nxt][stc1][0]);
    }
    v8h ahi[2], alo[2];
    #pragma unroll
    for (int tr = 0; tr < 2; ++tr){
      const size_t ab = (habase + tr*4 + kc)*512 + lnoff;
      ahi[tr] = *(const v8h*)&g_qh[ab];
      alo[tr] = *(const v8h*)&g_ql[ab];
    }
    #pragma unroll
    for (int tc = 0; tc < 8; ++tc){
      v8h bh = Bh[cur][tc][ln];
      v8h bl = Bl[cur][tc][ln];
      #pragma unroll
      for (int tr = 0; tr < 2; ++tr){
        acc[tr][tc] = __builtin_amdgcn_mfma_f32_16x16x32_f16(ahi[tr], bh, acc[tr][tc], 0, 0, 0);
        acc[tr][tc] = __builtin_amdgcn_mfma_f32_16x16x32_f16(ahi[tr], bl, acc[tr][tc], 0, 0, 0);
        acc[tr][tc] = __builtin_amdgcn_mfma_f32_16x16x32_f16(alo[tr], bh, acc[tr][tc], 0, 0, 0);
      }
    }
  }

  // epilogue: exp, shfl-reduced row sums -> g_lp (R1 order: bit-exact l)
  #pragma unroll
  for (int tr = 0; tr < 2; ++tr){
    float rs[4] = {0.f, 0.f, 0.f, 0.f};
    #pragma unroll
    for (int tc = 0; tc < 8; ++tc){
      #pragma unroll
      for (int r = 0; r < 4; ++r){
        rs[r] += __expf(acc[tr][tc][r]);
      }
    }
    #pragma unroll
    for (int r = 0; r < 4; ++r){
      float v = rs[r];
      v += __shfl_xor(v, 1);
      v += __shfl_xor(v, 2);
      v += __shfl_xor(v, 4);
      v += __shfl_xor(v, 8);
      rs[r] = v;
    }
    if (nidx == 0){
      #pragma unroll
      for (int r = 0; r < 4; ++r){
        const int row = (wv*2+tr)*16 + quad*4 + r;
        g_lp[((size_t)h*Nn + gp*128 + row)*16 + jb] = rs[r];
      }
    }
  }
}

// ---------------- Kernel 2r: MFMA QK recompute (B via global_load_lds) -> colsum -> g_bs ----------------
__global__ __launch_bounds__(256) void k2r_colsum(){
  const int bid0 = blockIdx.x;
  const int w = (bid0 & 7)*384 + (bid0 >> 3);   // 3072 blocks, xcd-contiguous
  const int jb = w & 15, gp = (w >> 4) & 15, h = w >> 8;
  const int t = threadIdx.x;
  const int wv = t >> 6, ln = t & 63;
  const int nidx = ln & 15, quad = ln >> 4;
  const size_t lnoff = (size_t)ln*8;
  const size_t habase = ((size_t)h*128 + gp*8 + wv*2)*4;
  const size_t hbbase = ((size_t)h*128 + jb*8)*4;

  __shared__ v8h Bh[2][8][64], Bl[2][8][64];
  __shared__ float il_s[128];
  __shared__ float part[4][128];
  const int stc0 = wv*2, stc1 = wv*2 + 1;

  // prologue: stage kc=0 into buffer 0 (async; latency overlaps il_s work)
  gload16(&g_kh[(hbbase + stc0*4 + 0)*512 + lnoff], &Bh[0][stc0][0]);
  gload16(&g_kh[(hbbase + stc1*4 + 0)*512 + lnoff], &Bh[0][stc1][0]);
  gload16(&g_kl[(hbbase + stc0*4 + 0)*512 + lnoff], &Bl[0][stc0][0]);
  gload16(&g_kl[(hbbase + stc1*4 + 0)*512 + lnoff], &Bl[0][stc1][0]);

  if (t < 128){
    const float* lp = &g_lp[((size_t)h*Nn + gp*128 + t)*16];
    float s = 0.f;
    #pragma unroll
    for (int x = 0; x < 16; ++x) s += lp[x];
    il_s[t] = 1.0f / s;
  }

  v4f acc[2][8];
  #pragma unroll
  for (int tr = 0; tr < 2; ++tr)
    #pragma unroll
    for (int tc = 0; tc < 8; ++tc)
      acc[tr][tc] = (v4f){0.f, 0.f, 0.f, 0.f};

  #pragma unroll
  for (int kc = 0; kc < 4; ++kc){
    const int cur = kc & 1;
    __syncthreads();   // buf[cur] complete (+ il_s covered by first barrier)
    if (kc < 3){
      const int nxt = cur ^ 1;
      gload16(&g_kh[(hbbase + stc0*4 + kc+1)*512 + lnoff], &Bh[nxt][stc0][0]);
      gload16(&g_kh[(hbbase + stc1*4 + kc+1)*512 + lnoff], &Bh[nxt][stc1][0]);
      gload16(&g_kl[(hbbase + stc0*4 + kc+1)*512 + lnoff], &Bl[nxt][stc0][0]);
      gload16(&g_kl[(hbbase + stc1*4 + kc+1)*512 + lnoff], &Bl[nxt][stc1][0]);
    }
    v8h ahi[2], alo[2];
    #pragma unroll
    for (int tr = 0; tr < 2; ++tr){
      const size_t ab = (habase + tr*4 + kc)*512 + lnoff;
      ahi[tr] = *(const v8h*)&g_qh[ab];
      alo[tr] = *(const v8h*)&g_ql[ab];
    }
    #pragma unroll
    for (int tc = 0; tc < 8; ++tc){
      v8h bh = Bh[cur][tc][ln];
      v8h bl = Bl[cur][tc][ln];
      #pragma unroll
      for (int tr = 0; tr < 2; ++tr){
        acc[tr][tc] = __builtin_amdgcn_mfma_f32_16x16x32_f16(ahi[tr], bh, acc[tr][tc], 0, 0, 0);
        acc[tr][tc] = __builtin_amdgcn_mfma_f32_16x16x32_f16(ahi[tr], bl, acc[tr][tc], 0, 0, 0);
        acc[tr][tc] = __builtin_amdgcn_mfma_f32_16x16x32_f16(alo[tr], bh, acc[tr][tc], 0, 0, 0);
      }
    }
  }

  // weighted colsum epilogue. Wave wv covers tile rows [wv*32, wv*32+32).
  __syncthreads();   // all compute done; il_s stable
  float csg[8];
  #pragma unroll
  for (int tc = 0; tc < 8; ++tc) csg[tc] = 0.f;
  #pragma unroll
  for (int tr = 0; tr < 2; ++tr){
    #pragma unroll
    for (int tc = 0; tc < 8; ++tc){
      float cs = 0.f;
      #pragma unroll
      for (int r = 0; r < 4; ++r){
        const int row = (wv*2+tr)*16 + quad*4 + r;
        cs += __expf(acc[tr][tc][r]) * il_s[row];
      }
      cs += __shfl_xor(cs, 16);   // sum across the 4 quads (16 rows of this tile-row)
      cs += __shfl_xor(cs, 32);
      csg[tc] += cs;
    }
  }
  if (ln < 16){                    // quad 0 publishes this wave's 128 col-partials
    #pragma unroll
    for (int tc = 0; tc < 8; ++tc) part[wv][tc*16 + nidx] = csg[tc];
  }
  __syncthreads();
  // waves 0+1 = rows 0..63 = group 2gp; waves 2+3 = group 2gp+1
  const int col = t & 127, grp = t >> 7;
  g_bs[((size_t)h*QGg + gp*2 + grp)*Nn + jb*128 + col] =
      part[grp*2][col] + part[grp*2 + 1][col];
}

// ---------------- Kernel 2b v3: radix select + equal-position list + mask -> key list ----------------
__global__ __launch_bounds__(256) void k2b_mask(){
  const int bid = blockIdx.x, g = bid % QGg, t = threadIdx.x;
  const int wv = t >> 6, lw = t & 63;
  __shared__ int hist[256];
  __shared__ int wsum[4];
  __shared__ int selb_s, selgt_s;
  __shared__ int csel;
  __shared__ int eqn;
  __shared__ int eqpos[Nn];      // positions with value == T (cap = Nn, can't overflow)
  const float* src = g_bs + (size_t)bid*Nn;
  float mine[8];
  {
    float4 a = *(const float4*)&src[t*4];
    float4 b = *(const float4*)&src[1024 + t*4];
    mine[0]=a.x; mine[1]=a.y; mine[2]=a.z; mine[3]=a.w;
    mine[4]=b.x; mine[5]=b.y; mine[6]=b.z; mine[7]=b.w;
  }
  if (t == 0){ csel = 0; eqn = 0; }
  unsigned int bu8[8];
  #pragma unroll
  for (int u = 0; u < 8; ++u) bu8[u] = __float_as_uint(mine[u]);

  unsigned int k1a, k1b, k2a, k2b;
  tf2x32(0u, 1u, 0u, 0u, k1a, k1b);
  tf2x32(0u, 1u, 0u, 1u, k2a, k2b);

  unsigned int pref = 0u;   // decided high bits of T
  unsigned int msk  = 0u;   // which bits are decided
  int rem = KSEL;           // rank (from largest) within current group
  #pragma unroll
  for (int pass = 3; pass >= 0; --pass){
    const int shift = pass*8;
    hist[t] = 0;
    __syncthreads();
    #pragma unroll
    for (int u = 0; u < 8; ++u){
      if ((bu8[u] & msk) == pref)
        atomicAdd(&hist[(bu8[u] >> shift) & 0xFFu], 1);
    }
    __syncthreads();
    const int hcnt = hist[t];
    int s = hcnt;                 // inclusive suffix sum within this wave's 64 bins
    #pragma unroll
    for (int d = 1; d < 64; d <<= 1){
      int tmp = __shfl_down(s, d);
      if (lw + d < 64) s += tmp;
    }
    if (lw == 0) wsum[wv] = s;    // total of this wave's 64 bins
    __syncthreads();
    int base = 0;
    #pragma unroll
    for (int w2 = 1; w2 < 4; ++w2) if (wv + w2 < 4) base += wsum[wv + w2];
    const int gt_incl = s + base;     // sum_{j >= t} hist[j]
    const int gt = gt_incl - hcnt;    // strict: sum_{j > t}
    if (gt < rem && gt_incl >= rem){ selb_s = t; selgt_s = gt; }
    __syncthreads();
    pref |= ((unsigned)selb_s) << shift;
    msk  |= 0xFFu << shift;
    rem  -= selgt_s;
  }
  const unsigned int T = pref;        // the KSEL-th largest value's bits
  const int need = rem;               // ties taken lowest-index-first (jax top_k)

  // collect positions of elements equal to T (multiplicity tiny; list order arbitrary)
  #pragma unroll
  for (int u = 0; u < 8; ++u){
    int j = (u < 4) ? (t*4 + u) : (1024 + t*4 + u - 4);
    if (bu8[u] == T){
      int s = atomicAdd(&eqn, 1);
      eqpos[s] = j;
    }
  }
  __syncthreads();
  const int en = eqn;

  const int lo = g*BMq + BMq/2 - 153;   // ws=int(0.15*2048)=307, ws//2=153
  const int hi = g*BMq + BMq/2 + 153;
  const int ssum = ((hi < Nn) ? hi : Nn) - ((lo > 0) ? lo : 0);
  const bool vqg = (ssum + KSEL) < Nn;  // always true at this config

  #pragma unroll
  for (int u = 0; u < 8; ++u){
    int j = (u < 4) ? (t*4 + u) : (1024 + t*4 + u - 4);
    unsigned int bu = bu8[u];
    bool topk = bu > T;
    if (!topk && bu == T){
      int tr = 0;
      for (int i = 0; i < en; ++i)
        tr += (eqpos[i] < j) ? 1 : 0;
      topk = (tr < need);
    }
    bool rnd = jax_rand01((unsigned)(bid*Nn + j), k1a, k1b, k2a, k2b);
    bool st  = (j >= lo) && (j < hi);
    bool selb = st || ((rnd || topk) && vqg);
    if (selb){
      int slot = atomicAdd(&csel, 1);
      g_sel[(size_t)bid*Nn + slot] = (unsigned short)j;
    }
  }
  __syncthreads();
  if (t == 0) g_cnt[bid] = csel;
}

// ---------------- Kernel 3 v4: MFMA attention, single-fp16 PV, ~30KB LDS (5 blocks/CU) ----------------
// QK stays split-fp16 (scores feed exp). PV = P_hi x V_hi only (output-precision path).
// p_l / vTl deleted. Same 3-barrier chunk lockstep, V swizzle, T14 staging.
__global__ __launch_bounds__(256) void k3_attn(const float* __restrict__ K,
                                               const float* __restrict__ V,
                                               const float* __restrict__ OC,
                                               float* __restrict__ out){
  const int bid0 = blockIdx.x;
  const int w    = (bid0 & 7)*96 + (bid0 >> 3);   // xcd-grouped work index
  const int half = w & 1;
  const int gg   = w >> 1;             // h*QGg + g
  const int h = gg / QGg, g = gg % QGg;
  const int t = threadIdx.x;
  const int wv = t >> 6, ln = t & 63;
  const int nidx = ln & 15, quad = ln >> 4;
  const int qtile = wv >> 1, kdt = wv & 1;

  __shared__ _Float16 kh_s[CK][136];   // K hi, row stride 272B (16B-aligned)
  __shared__ _Float16 kl_s[CK][136];   // K lo
  __shared__ _Float16 vTh[Dd][40];     // V hi transposed+swizzled, row 80B (16B-aligned)
  __shared__ _Float16 p_h[32][40];     // P hi
  __shared__ float    l_part[2][32];
  __shared__ float    l_s[32];

  const int c = g_cnt[gg];
  const unsigned short* sel = g_sel + (size_t)gg*Nn;

  // hoisted Q A-fragments (pre-scaled split-fp16, fragment-ordered, L2-hot)
  const int rb = g*4 + half*2 + qtile;
  v8h aHi[4], aLo[4];
  #pragma unroll
  for (int kc = 0; kc < 4; ++kc){
    const size_t ab = (((size_t)h*128 + rb)*4 + kc)*512 + (size_t)ln*8;
    aHi[kc] = *(const v8h*)&g_qh[ab];
    aLo[kc] = *(const v8h*)&g_ql[ab];
  }

  if (t < 64) l_part[t >> 5][t & 31] = 0.0f;

  // prologue: stage chunk 0 into registers
  float4 kreg[4], vreg[4];
  {
    const int cc0 = (c < CK) ? c : CK;
    #pragma unroll
    for (int it = 0; it < 4; ++it){
      int e = it*256 + t, row = e >> 5, c4 = e & 31;
      int j = (row < cc0) ? (int)sel[row] : 0;
      kreg[it] = ((const float4*)(K + ((size_t)h*Nn + j)*Dd))[c4];
      vreg[it] = ((const float4*)(V + ((size_t)h*Nn + j)*Dd))[c4];
    }
  }

  v4f acc[4];
  #pragma unroll
  for (int dt = 0; dt < 4; ++dt) acc[dt] = (v4f){0.f, 0.f, 0.f, 0.f};

  // PV read column group (swizzle self-undoing)
  const int cg = (quad ^ ((nidx >> 2) & 3)) * 8;

  for (int c0 = 0; c0 < c; c0 += CK){
    const int cc = ((c - c0) < CK) ? (c - c0) : CK;
    // ---- phase 1: regs -> LDS (K cvt once split; V hi-only, transposed+swizzled) ----
    #pragma unroll
    for (int it = 0; it < 4; ++it){
      int e = it*256 + t, row = e >> 5, c4 = e & 31;
      float4 kv = kreg[it];
      float xs[4] = {kv.x, kv.y, kv.z, kv.w};
      _Float16 hh[4], ll[4];
      #pragma unroll
      for (int m = 0; m < 4; ++m){
        _Float16 hi = (_Float16)xs[m];
        hh[m] = hi;
        ll[m] = (_Float16)(xs[m] - (float)hi);
      }
      *(unsigned*)&kh_s[row][c4*4 + 0] = pack2h(hh[0], hh[1]);
      *(unsigned*)&kh_s[row][c4*4 + 2] = pack2h(hh[2], hh[3]);
      *(unsigned*)&kl_s[row][c4*4 + 0] = pack2h(ll[0], ll[1]);
      *(unsigned*)&kl_s[row][c4*4 + 2] = pack2h(ll[2], ll[3]);
      float4 vv = vreg[it];
      const int swz = row ^ ((c4 & 3) << 3);   // d = c4*4+m -> (d>>2)&3 == c4&3
      vTh[c4*4 + 0][swz] = (_Float16)vv.x;
      vTh[c4*4 + 1][swz] = (_Float16)vv.y;
      vTh[c4*4 + 2][swz] = (_Float16)vv.z;
      vTh[c4*4 + 3][swz] = (_Float16)vv.w;
    }
    __syncthreads();   // barrier A: LDS ready
    // ---- T14: issue next chunk's gathers into regs (latency hides under QK+PV) ----
    {
      const int nc0 = c0 + CK;
      if (nc0 < c){
        const int ncc = ((c - nc0) < CK) ? (c - nc0) : CK;
        #pragma unroll
        for (int it = 0; it < 4; ++it){
          int e = it*256 + t, row = e >> 5, c4 = e & 31;
          int j = (row < ncc) ? (int)sel[nc0 + row] : 0;
          kreg[it] = ((const float4*)(K + ((size_t)h*Nn + j)*Dd))[c4];
          vreg[it] = ((const float4*)(V + ((size_t)h*Nn + j)*Dd))[c4];
        }
      }
    }
    // ---- phase 2: QK split-fp16 MFMA; epilogue exp -> p_h + shfl l-reduce ----
    v4f sc = (v4f){0.f, 0.f, 0.f, 0.f};
    #pragma unroll
    for (int kc = 0; kc < 4; ++kc){
      v8h bh = *(const v8h*)&kh_s[kdt*16 + nidx][kc*32 + quad*8];
      v8h bl = *(const v8h*)&kl_s[kdt*16 + nidx][kc*32 + quad*8];
      sc = __builtin_amdgcn_mfma_f32_16x16x32_f16(aHi[kc], bh, sc, 0, 0, 0);
      sc = __builtin_amdgcn_mfma_f32_16x16x32_f16(aHi[kc], bl, sc, 0, 0, 0);
      sc = __builtin_amdgcn_mfma_f32_16x16x32_f16(aLo[kc], bh, sc, 0, 0, 0);
    }
    {
      const int k_loc = kdt*16 + nidx;
      float rs[4];
      #pragma unroll
      for (int r = 0; r < 4; ++r){
        float sv = (k_loc < cc) ? __expf(sc[r]) : 0.f;
        rs[r] = sv;
        const int row = qtile*16 + quad*4 + r;
        p_h[row][k_loc] = (_Float16)sv;
      }
      #pragma unroll
      for (int r = 0; r < 4; ++r){
        float v = rs[r];
        v += __shfl_xor(v, 1);
        v += __shfl_xor(v, 2);
        v += __shfl_xor(v, 4);
        v += __shfl_xor(v, 8);
        rs[r] = v;
      }
      if (nidx == 0){
        #pragma unroll
        for (int r = 0; r < 4; ++r)
          l_part[kdt][qtile*16 + quad*4 + r] += rs[r];
      }
    }
    __syncthreads();   // barrier B: P ready, QK reads of kh/kl done
    // ---- phase 3: PV — single-fp16, 4 MFMA, all-vector LDS reads ----
    {
      v8h ph = *(const v8h*)&p_h[qtile*16 + nidx][quad*8];
      #pragma unroll
      for (int dt = 0; dt < 4; ++dt){
        const int d = (kdt*4 + dt)*16 + nidx;
        v8h vh = *(const v8h*)&vTh[d][cg];
        acc[dt] = __builtin_amdgcn_mfma_f32_16x16x32_f16(ph, vh, acc[dt], 0, 0, 0);
      }
    }
    __syncthreads();   // barrier C: LDS consumed, safe to overwrite
  }

  if (t < 32) l_s[t] = 1.0f / (l_part[0][t] + l_part[1][t]);
  __syncthreads();

  #pragma unroll
  for (int dt = 0; dt < 4; ++dt){
    const int d = (kdt*4 + dt)*16 + nidx;
    #pragma unroll
    for (int r = 0; r < 4; ++r){
      const int row = qtile*16 + quad*4 + r;
      const float il = l_s[row];
      const size_t o = ((size_t)h*Nn + (size_t)g*BMq + half*32 + row)*Dd + d;
      out[o] = acc[dt][r]*il + OC[o];
    }
  }
}

extern "C" void kernel_launch(void* const* d_in, const int* in_sizes, int n_in,
                              void* d_out, int out_size, void* d_ws, size_t ws_size,
                              hipStream_t stream) {
  (void)in_sizes; (void)n_in; (void)out_size; (void)d_ws; (void)ws_size;
  const float* Q  = (const float*)d_in[0];
  const float* K  = (const float*)d_in[1];
  const float* V  = (const float*)d_in[2];
  const float* OC = (const float*)d_in[3];
  float* out = (float*)d_out;
  hipLaunchKernelGGL(k0_cvt,     dim3(Hh*128),   dim3(256), 0, stream, Q, K);
  hipLaunchKernelGGL(k1_rowsum,  dim3(Hh*16*16), dim3(256), 0, stream);
  hipLaunchKernelGGL(k2r_colsum, dim3(Hh*16*16), dim3(256), 0, stream);
  hipLaunchKernelGGL(k2b_mask,   dim3(Hh*QGg),   dim3(256), 0, stream);
  hipLaunchKernelGGL(k3_attn,    dim3(Hh*QGg*2), dim3(256), 0, stream, K, V, OC, out);
}